// Round 7
// baseline (156.134 us; speedup 1.0000x reference)
//
#include <hip/hip_runtime.h>
#include <math.h>

#define BATCH 256
#define FDIM 16384
#define MSLOTS 2000
#define MPAD 2048
#define NCLS 10
#define MPC 200   // memories per class

static constexpr float THRESH = 2e-4f;
static constexpr float ENTC   = 2e-4f;
static constexpr float CEPS   = 1e-8f;
static constexpr float LEPS   = 1e-12f;

using bf16x8 = __attribute__((ext_vector_type(8))) short;
using f32x4  = __attribute__((ext_vector_type(4))) float;
using us8    = __attribute__((ext_vector_type(8))) unsigned short;

__device__ __forceinline__ unsigned short f2bf(float f) {
  unsigned u = __float_as_uint(f);
  unsigned r = u + 0x7fffu + ((u >> 16) & 1u);
  return (unsigned short)(r >> 16);
}

__device__ __forceinline__ void gload_lds16(const unsigned short* g, unsigned short* l) {
  __builtin_amdgcn_global_load_lds(
      (const __attribute__((address_space(1))) void*)g,
      (__attribute__((address_space(3))) void*)l, 16, 0, 0);
}

__device__ __forceinline__ float waveReduceSum(float v) {
#pragma unroll
  for (int o = 32; o > 0; o >>= 1) v += __shfl_xor(v, o);
  return v;
}
__device__ __forceinline__ float waveReduceMax(float v) {
#pragma unroll
  for (int o = 32; o > 0; o >>= 1) v = fmaxf(v, __shfl_xor(v, o));
  return v;
}

// ======================= bf16 MFMA PATH =======================

// ---- streaming convert, deep load pipeline: load ALL 16 float4 into registers
// (back-to-back global_load_dwordx4, one waitcnt), then convert+store.
// rows 0..MPAD-1 -> mem (tail rows zero-filled), rows MPAD..MPAD+BATCH-1 -> z
__global__ __launch_bounds__(256) void convert_stream_kernel(
    const float* __restrict__ z, const float* __restrict__ mem,
    unsigned short* __restrict__ zb, unsigned short* __restrict__ mb,
    float* __restrict__ nm, float* __restrict__ nz) {
  const int tid = threadIdx.x;
  __shared__ float red[2][4];
#pragma unroll
  for (int rr = 0; rr < 2; ++rr) {
    const int row = blockIdx.x * 2 + rr;
    const bool isMem = (row < MPAD);
    unsigned short* orow = isMem ? (mb + (size_t)row * FDIM)
                                 : (zb + (size_t)(row - MPAD) * FDIM);
    if (isMem && row >= MSLOTS) {   // zero tail
      const uint4 zed = make_uint4(0u, 0u, 0u, 0u);
      for (int i = tid; i < FDIM / 8; i += 256)
        *reinterpret_cast<uint4*>(&orow[i * 8]) = zed;
      if (tid == 0) nm[row] = 1.0f;
      continue;
    }
    const float* srow = isMem ? (mem + (size_t)row * FDIM)
                              : (z + (size_t)(row - MPAD) * FDIM);
    // phase A: issue all 16 lane-contiguous 16B loads (16KB/wave in flight)
    float4 x[16];
#pragma unroll
    for (int j = 0; j < 16; ++j)
      x[j] = *reinterpret_cast<const float4*>(&srow[(tid + j * 256) * 4]);
    // phase B: convert + store (stores are fire-and-forget)
    float s = 0.f;
#pragma unroll
    for (int j = 0; j < 16; ++j) {
      const float4 v = x[j];
      s = fmaf(v.x, v.x, fmaf(v.y, v.y, fmaf(v.z, v.z, fmaf(v.w, v.w, s))));
      uint2 o;
      o.x = ((unsigned)f2bf(v.y) << 16) | f2bf(v.x);
      o.y = ((unsigned)f2bf(v.w) << 16) | f2bf(v.z);
      *reinterpret_cast<uint2*>(&orow[(tid + j * 256) * 4]) = o;
    }
    s = waveReduceSum(s);
    if ((tid & 63) == 0) red[rr][tid >> 6] = s;
    __syncthreads();
    if (tid == 0) {
      float v = sqrtf(red[rr][0] + red[rr][1] + red[rr][2] + red[rr][3]);
      if (isMem) nm[row] = v;
      else       nz[row - MPAD] = v;
    }
  }
}

// ---- standalone transpose mb[m][f] -> mt[f][m], 128m x 64f tiles ----
#define TR_M 128
#define TR_F 64
__global__ __launch_bounds__(256) void transpose_kernel(const unsigned short* __restrict__ mb,
                                                        unsigned short* __restrict__ mt) {
  __shared__ unsigned int P[TR_M * 34];   // row stride 34 u32 = 136 B
  const int tid = threadIdx.x;
  const int f0 = blockIdx.x * TR_F;
  const int m0 = blockIdx.y * TR_M;
#pragma unroll
  for (int it = 0; it < 4; ++it) {
    const int r = (tid >> 3) + it * 32;   // 0..127
    const int c8 = tid & 7;               // 16B chunk -> quads 2c8, 2c8+1
    const uint4 v = *reinterpret_cast<const uint4*>(
        &mb[(size_t)(m0 + r) * FDIM + f0 + c8 * 8]);
    const int x = (r >> 1) & 15;
    *reinterpret_cast<uint2*>(&P[r * 34 + 2 * ((2 * c8) ^ x)])     = make_uint2(v.x, v.y);
    *reinterpret_cast<uint2*>(&P[r * 34 + 2 * ((2 * c8 + 1) ^ x)]) = make_uint2(v.z, v.w);
  }
  __syncthreads();
#pragma unroll
  for (int half = 0; half < 2; ++half) {
    const int h = tid & 15;               // m-octet 0..15
    const int fp = (tid >> 4) + half * 16;  // f-pair 0..31
    unsigned p[8];
#pragma unroll
    for (int s = 0; s < 8; ++s) {
      const int m = h * 8 + s;
      const int col = fp ^ ((((m >> 1) & 15)) << 1);
      p[s] = P[m * 34 + col];
    }
    unsigned lo[4], hi[4];
#pragma unroll
    for (int t = 0; t < 4; ++t) {
      const unsigned p0 = p[2 * t], p1 = p[2 * t + 1];
      lo[t] = (p1 << 16) | (p0 & 0xFFFFu);         // f = 2*fp
      hi[t] = (p1 & 0xFFFF0000u) | (p0 >> 16);     // f = 2*fp+1
    }
    const size_t base = (size_t)(f0 + 2 * fp) * MPAD + m0 + h * 8;
    *reinterpret_cast<uint4*>(&mt[base])        = make_uint4(lo[0], lo[1], lo[2], lo[3]);
    *reinterpret_cast<uint4*>(&mt[base + MPAD]) = make_uint4(hi[0], hi[1], hi[2], hi[3]);
  }
}

// ---- GEMM1 (MFMA): partial[s][b][m] = sum_k z_bf16[b][k] * mem_bf16[m][k] ----
#define G1_BM 128
#define G1_BN 64
#define G1_BK 64
#define SPLITK 8
#define KCHUNK (FDIM / SPLITK)   // 2048

__global__ __launch_bounds__(256, 2) void gemm1_mfma(const unsigned short* __restrict__ zb,
                                                     const unsigned short* __restrict__ mb,
                                                     float* __restrict__ part) {
  __shared__ unsigned short As[G1_BM * G1_BK];  // rows of 64 bf16 (128 B), slot-swizzled
  __shared__ unsigned short Bs[G1_BN * G1_BK];
  const int tid = threadIdx.x;
  const int lane = tid & 63, wid = tid >> 6;
  const int bn0 = blockIdx.x * G1_BN;
  const int bm0 = blockIdx.y * G1_BM;
  const int kbase = blockIdx.z * KCHUNK;
  const int wr = wid >> 1, wc = wid & 1;  // wave tile 64x32
  const int l8 = lane >> 3, l7 = lane & 7;
  const int r16 = lane & 15, klane = lane >> 4;

  f32x4 acc[4][2] = {};

  for (int kt = 0; kt < KCHUNK; kt += G1_BK) {
    const int kg = kbase + kt;
#pragma unroll
    for (int it = 0; it < 4; ++it) {
      int c = wid + it * 4;
      int r = c * 8 + l8;
      int src = (l7 ^ (r & 7)) << 3;
      gload_lds16(&zb[(size_t)(bm0 + r) * FDIM + kg + src], &As[c * 512]);
    }
#pragma unroll
    for (int it = 0; it < 2; ++it) {
      int c = wid + it * 4;
      int r = c * 8 + l8;
      int src = (l7 ^ (r & 7)) << 3;
      gload_lds16(&mb[(size_t)(bn0 + r) * FDIM + kg + src], &Bs[c * 512]);
    }
    __syncthreads();
#pragma unroll
    for (int s = 0; s < 2; ++s) {
      bf16x8 a[4], bb[2];
#pragma unroll
      for (int i = 0; i < 4; ++i) {
        int r = wr * 64 + i * 16 + r16;
        int p = (s * 4 + klane) ^ (r & 7);
        a[i] = *reinterpret_cast<const bf16x8*>(&As[r * 64 + p * 8]);
      }
#pragma unroll
      for (int j = 0; j < 2; ++j) {
        int r = wc * 32 + j * 16 + r16;
        int p = (s * 4 + klane) ^ (r & 7);
        bb[j] = *reinterpret_cast<const bf16x8*>(&Bs[r * 64 + p * 8]);
      }
#pragma unroll
      for (int i = 0; i < 4; ++i)
#pragma unroll
        for (int j = 0; j < 2; ++j)
          acc[i][j] = __builtin_amdgcn_mfma_f32_16x16x32_bf16(a[i], bb[j], acc[i][j], 0, 0, 0);
    }
    __syncthreads();
  }
  const int rgrp = lane >> 4;
  float* pbase = part + (size_t)blockIdx.z * BATCH * MPAD;
#pragma unroll
  for (int i = 0; i < 4; ++i)
#pragma unroll
    for (int j = 0; j < 2; ++j)
#pragma unroll
      for (int rg = 0; rg < 4; ++rg) {
        int row = bm0 + wr * 64 + i * 16 + rgrp * 4 + rg;
        int col = bn0 + wc * 32 + j * 16 + r16;
        pbase[(size_t)row * MPAD + col] = acc[i][j][rg];
      }
}

// ---- softmax: fuse split-K reduce + norm divide; write bf16 w_t / w_nt; entropy fp32 ----
__global__ __launch_bounds__(256) void softmax2_kernel(const float* __restrict__ part,
                                                       const float* __restrict__ nzv,
                                                       const float* __restrict__ nmv,
                                                       const int* __restrict__ labels,
                                                       unsigned short* __restrict__ wt,
                                                       unsigned short* __restrict__ wn,
                                                       float* __restrict__ ent) {
  const int b = blockIdx.x, tid = threadIdx.x;
  __shared__ float sh[MSLOTS];
  __shared__ float red[4], red2[4];
  const float nzb = nzv[b];
  float mx = -3.4e38f;
  for (int m = tid; m < MSLOTS; m += 256) {
    float s = 0.f;
#pragma unroll
    for (int sp = 0; sp < SPLITK; ++sp)
      s += part[((size_t)sp * BATCH + b) * MPAD + m];
    float v = s / fmaxf(nzb * nmv[m], CEPS);
    sh[m] = v; mx = fmaxf(mx, v);
  }
  mx = waveReduceMax(mx);
  if ((tid & 63) == 0) red[tid >> 6] = mx;
  __syncthreads();
  mx = fmaxf(fmaxf(red[0], red[1]), fmaxf(red[2], red[3]));
  __syncthreads();

  float s = 0.f;
  for (int m = tid; m < MSLOTS; m += 256) {
    float e = expf(sh[m] - mx); sh[m] = e; s += e;
  }
  s = waveReduceSum(s);
  if ((tid & 63) == 0) red[tid >> 6] = s;
  __syncthreads();
  s = red[0] + red[1] + red[2] + red[3];
  __syncthreads();

  const float inv = 1.f / s;
  const int c = labels[b];
  const int t0 = c * MPC, t1 = t0 + MPC;
  float st = 0.f, sn = 0.f;
  for (int m = tid; m < MSLOTS; m += 256) {
    float w = sh[m] * inv;
    float k = (w > THRESH) ? w : 0.f;
    sh[m] = k;
    bool tgt = (m >= t0) && (m < t1);
    st += tgt ? k : 0.f;
    sn += tgt ? 0.f : k;
  }
  st = waveReduceSum(st); sn = waveReduceSum(sn);
  if ((tid & 63) == 0) { red[tid >> 6] = st; red2[tid >> 6] = sn; }
  __syncthreads();
  st = red[0] + red[1] + red[2] + red[3];
  sn = red2[0] + red2[1] + red2[2] + red2[3];
  __syncthreads();

  const float rt = 1.f / st, rn = 1.f / sn;
  float et = 0.f, en = 0.f;
  unsigned short* wtr = wt + (size_t)b * MPAD;
  unsigned short* wnr = wn + (size_t)b * MPAD;
  for (int m = tid; m < MPAD; m += 256) {
    float a = 0.f, cn = 0.f;
    if (m < MSLOTS) {
      float k = sh[m];
      bool tgt = (m >= t0) && (m < t1);
      a  = tgt ? k * rt : 0.f;
      cn = tgt ? 0.f : k * rn;
      et -= a  * logf(a  + LEPS);
      en -= cn * logf(cn + LEPS);
    }
    wtr[m] = f2bf(a);
    wnr[m] = f2bf(cn);
  }
  et = waveReduceSum(et); en = waveReduceSum(en);
  if ((tid & 63) == 0) { red[tid >> 6] = et; red2[tid >> 6] = en; }
  __syncthreads();
  if (tid == 0) {
    ent[b]         = red[0] + red[1] + red[2] + red[3];
    ent[BATCH + b] = red2[0] + red2[1] + red2[2] + red2[3];
  }
}

// ---- GEMM2+3 (MFMA, fused dual accumulator): z_hat = w @ mem via memT ----
#define G2_BM 128
#define G2_BN 128
#define G2_BK 64

__global__ __launch_bounds__(512, 2) void gemm23_mfma(const unsigned short* __restrict__ wt,
                                                      const unsigned short* __restrict__ wn,
                                                      const unsigned short* __restrict__ mt,
                                                      float* __restrict__ out) {
  __shared__ unsigned short At[G2_BM * G2_BK];
  __shared__ unsigned short An[G2_BM * G2_BK];
  __shared__ unsigned short Bs[G2_BN * G2_BK];
  const int tid = threadIdx.x, lane = tid & 63, wid = tid >> 6;
  const int bn0 = blockIdx.x * G2_BN;  // f
  const int bm0 = blockIdx.y * G2_BM;  // batch
  const int wr = wid >> 2, wc = wid & 3;  // 2x4 waves, each 64x32
  const int l8 = lane >> 3, l7 = lane & 7;
  const int r16 = lane & 15, klane = lane >> 4;

  f32x4 acct[4][2] = {}, accn[4][2] = {};

  for (int k0 = 0; k0 < MPAD; k0 += G2_BK) {
#pragma unroll
    for (int it = 0; it < 2; ++it) {
      int c = wid + it * 8;  // 16 chunks over 8 waves
      int r = c * 8 + l8;
      int src = (l7 ^ (r & 7)) << 3;
      gload_lds16(&wt[(size_t)(bm0 + r) * MPAD + k0 + src], &At[c * 512]);
      gload_lds16(&wn[(size_t)(bm0 + r) * MPAD + k0 + src], &An[c * 512]);
      gload_lds16(&mt[(size_t)(bn0 + r) * MPAD + k0 + src], &Bs[c * 512]);
    }
    __syncthreads();
#pragma unroll
    for (int s = 0; s < 2; ++s) {
      bf16x8 at[4], an[4], bb[2];
#pragma unroll
      for (int i = 0; i < 4; ++i) {
        int r = wr * 64 + i * 16 + r16;
        int p = (s * 4 + klane) ^ (r & 7);
        at[i] = *reinterpret_cast<const bf16x8*>(&At[r * 64 + p * 8]);
        an[i] = *reinterpret_cast<const bf16x8*>(&An[r * 64 + p * 8]);
      }
#pragma unroll
      for (int j = 0; j < 2; ++j) {
        int r = wc * 32 + j * 16 + r16;
        int p = (s * 4 + klane) ^ (r & 7);
        bb[j] = *reinterpret_cast<const bf16x8*>(&Bs[r * 64 + p * 8]);
      }
#pragma unroll
      for (int i = 0; i < 4; ++i)
#pragma unroll
        for (int j = 0; j < 2; ++j) {
          acct[i][j] = __builtin_amdgcn_mfma_f32_16x16x32_bf16(at[i], bb[j], acct[i][j], 0, 0, 0);
          accn[i][j] = __builtin_amdgcn_mfma_f32_16x16x32_bf16(an[i], bb[j], accn[i][j], 0, 0, 0);
        }
    }
    __syncthreads();
  }
  float* outn = out + (size_t)BATCH * FDIM;
  const int rgrp = lane >> 4;
#pragma unroll
  for (int i = 0; i < 4; ++i)
#pragma unroll
    for (int j = 0; j < 2; ++j)
#pragma unroll
      for (int rg = 0; rg < 4; ++rg) {
        size_t off = (size_t)(bm0 + wr * 64 + i * 16 + rgrp * 4 + rg) * FDIM
                   + bn0 + wc * 32 + j * 16 + r16;
        out[off]  = acct[i][j][rg];
        outn[off] = accn[i][j][rg];
      }
}

// ---- entropy final reduce ----
__global__ __launch_bounds__(256) void entreduce_kernel(const float* __restrict__ ent,
                                                        float* __restrict__ out) {
  const int tid = threadIdx.x;
  float v = ent[tid];
  float u = ent[BATCH + tid];
  v = waveReduceSum(v); u = waveReduceSum(u);
  __shared__ float r1[4], r2[4];
  if ((tid & 63) == 0) { r1[tid >> 6] = v; r2[tid >> 6] = u; }
  __syncthreads();
  if (tid == 0) {
    out[(size_t)2 * BATCH * FDIM]     = ENTC * (r1[0] + r1[1] + r1[2] + r1[3]);
    out[(size_t)2 * BATCH * FDIM + 1] = ENTC * (r2[0] + r2[1] + r2[2] + r2[3]);
  }
}

// ======================= OLD fp32 FALLBACK PATH =======================
#define NM_OFF    0
#define NZ_OFF    2048
#define LOGIT_OFF 4096
#define WT_OFF    (LOGIT_OFF + 512000)
#define WNT_OFF   (WT_OFF + 512000)
#define ENT_OFF   (WNT_OFF + 512000)

__global__ __launch_bounds__(256) void rownorm_kernel(const float* __restrict__ x,
                                                      float* __restrict__ out, int cols) {
  const int r = blockIdx.x;
  const float4* xr = reinterpret_cast<const float4*>(x) + (size_t)r * (cols >> 2);
  const int n4 = cols >> 2;
  float s = 0.f;
  for (int i = threadIdx.x; i < n4; i += 256) {
    float4 v = xr[i];
    s = fmaf(v.x, v.x, s); s = fmaf(v.y, v.y, s);
    s = fmaf(v.z, v.z, s); s = fmaf(v.w, v.w, s);
  }
  s = waveReduceSum(s);
  __shared__ float red[4];
  if ((threadIdx.x & 63) == 0) red[threadIdx.x >> 6] = s;
  __syncthreads();
  if (threadIdx.x == 0) out[r] = sqrtf(red[0] + red[1] + red[2] + red[3]);
}

#define O1_BM 64
#define O1_BN 32
#define O1_BK 64
__global__ __launch_bounds__(256) void gemm1_kernel(const float* __restrict__ z,
                                                    const float* __restrict__ mem,
                                                    const float* __restrict__ nzv,
                                                    const float* __restrict__ nmv,
                                                    float* __restrict__ logit) {
  __shared__ float As[O1_BK][O1_BM];
  __shared__ float Bs[O1_BK][O1_BN];
  const int tid = threadIdx.x;
  const int bm0 = blockIdx.y * O1_BM;
  const int bn0 = blockIdx.x * O1_BN;
  const int tm = tid >> 4, tn = tid & 15;
  float acc[4][2] = {};
  for (int k0 = 0; k0 < FDIM; k0 += O1_BK) {
#pragma unroll
    for (int it = 0; it < 4; ++it) {
      int i = tid + it * 256;
      int row = i >> 4, c4 = i & 15;
      float4 v = *reinterpret_cast<const float4*>(&z[(size_t)(bm0 + row) * FDIM + k0 + c4 * 4]);
      As[c4 * 4 + 0][row] = v.x; As[c4 * 4 + 1][row] = v.y;
      As[c4 * 4 + 2][row] = v.z; As[c4 * 4 + 3][row] = v.w;
    }
#pragma unroll
    for (int it = 0; it < 2; ++it) {
      int i = tid + it * 256;
      int row = i >> 4, c4 = i & 15;
      int gm = bn0 + row;
      float4 v = make_float4(0.f, 0.f, 0.f, 0.f);
      if (gm < MSLOTS)
        v = *reinterpret_cast<const float4*>(&mem[(size_t)gm * FDIM + k0 + c4 * 4]);
      Bs[c4 * 4 + 0][row] = v.x; Bs[c4 * 4 + 1][row] = v.y;
      Bs[c4 * 4 + 2][row] = v.z; Bs[c4 * 4 + 3][row] = v.w;
    }
    __syncthreads();
#pragma unroll
    for (int kk = 0; kk < O1_BK; ++kk) {
      const float* ap = &As[kk][tm * 4];
      const float* bp = &Bs[kk][tn * 2];
      float a0 = ap[0], a1 = ap[1], a2 = ap[2], a3 = ap[3];
      float b0 = bp[0], b1 = bp[1];
      acc[0][0] = fmaf(a0, b0, acc[0][0]); acc[0][1] = fmaf(a0, b1, acc[0][1]);
      acc[1][0] = fmaf(a1, b0, acc[1][0]); acc[1][1] = fmaf(a1, b1, acc[1][1]);
      acc[2][0] = fmaf(a2, b0, acc[2][0]); acc[2][1] = fmaf(a2, b1, acc[2][1]);
      acc[3][0] = fmaf(a3, b0, acc[3][0]); acc[3][1] = fmaf(a3, b1, acc[3][1]);
    }
    __syncthreads();
  }
  float nzr[4];
#pragma unroll
  for (int i = 0; i < 4; ++i) nzr[i] = nzv[bm0 + tm * 4 + i];
#pragma unroll
  for (int j = 0; j < 2; ++j) {
    int col = bn0 + tn * 2 + j;
    if (col < MSLOTS) {
      float nmr = nmv[col];
#pragma unroll
      for (int i = 0; i < 4; ++i)
        logit[(size_t)(bm0 + tm * 4 + i) * MSLOTS + col] = acc[i][j] / fmaxf(nzr[i] * nmr, CEPS);
    }
  }
}

__global__ __launch_bounds__(256) void softmax_kernel(const float* __restrict__ logit,
                                                      const int* __restrict__ labels,
                                                      float* __restrict__ wt,
                                                      float* __restrict__ wnt,
                                                      float* __restrict__ ent) {
  const int b = blockIdx.x;
  const int tid = threadIdx.x;
  __shared__ float sh[MSLOTS];
  __shared__ float red[4], red2[4];
  const float* lrow = logit + (size_t)b * MSLOTS;
  float mx = -3.4e38f;
  for (int m = tid; m < MSLOTS; m += 256) {
    float v = lrow[m]; sh[m] = v; mx = fmaxf(mx, v);
  }
  mx = waveReduceMax(mx);
  if ((tid & 63) == 0) red[tid >> 6] = mx;
  __syncthreads();
  mx = fmaxf(fmaxf(red[0], red[1]), fmaxf(red[2], red[3]));
  __syncthreads();
  float s = 0.f;
  for (int m = tid; m < MSLOTS; m += 256) {
    float e = expf(sh[m] - mx); sh[m] = e; s += e;
  }
  s = waveReduceSum(s);
  if ((tid & 63) == 0) red[tid >> 6] = s;
  __syncthreads();
  s = red[0] + red[1] + red[2] + red[3];
  __syncthreads();
  const float inv = 1.f / s;
  const int c = labels[b];
  const int t0 = c * MPC, t1 = t0 + MPC;
  float st = 0.f, sn = 0.f;
  for (int m = tid; m < MSLOTS; m += 256) {
    float w = sh[m] * inv;
    float k = (w > THRESH) ? w : 0.f;
    sh[m] = k;
    bool tgt = (m >= t0) && (m < t1);
    st += tgt ? k : 0.f;
    sn += tgt ? 0.f : k;
  }
  st = waveReduceSum(st); sn = waveReduceSum(sn);
  if ((tid & 63) == 0) { red[tid >> 6] = st; red2[tid >> 6] = sn; }
  __syncthreads();
  st = red[0] + red[1] + red[2] + red[3];
  sn = red2[0] + red2[1] + red2[2] + red2[3];
  __syncthreads();
  const float rt = 1.f / st, rn = 1.f / sn;
  float et = 0.f, en = 0.f;
  float* wtr = wt + (size_t)b * MSLOTS;
  float* wnr = wnt + (size_t)b * MSLOTS;
  for (int m = tid; m < MSLOTS; m += 256) {
    float k = sh[m];
    bool tgt = (m >= t0) && (m < t1);
    float a  = tgt ? k * rt : 0.f;
    float cn = tgt ? 0.f : k * rn;
    wtr[m] = a;
    wnr[m] = cn;
    et -= a  * logf(a  + LEPS);
    en -= cn * logf(cn + LEPS);
  }
  et = waveReduceSum(et); en = waveReduceSum(en);
  if ((tid & 63) == 0) { red[tid >> 6] = et; red2[tid >> 6] = en; }
  __syncthreads();
  if (tid == 0) {
    ent[b]         = red[0] + red[1] + red[2] + red[3];
    ent[BATCH + b] = red2[0] + red2[1] + red2[2] + red2[3];
  }
}

#define O2_BM 64
#define O2_BN 64
#define O2_BK 32
__global__ __launch_bounds__(256) void gemm23_kernel(const float* __restrict__ wt,
                                                     const float* __restrict__ wnt,
                                                     const float* __restrict__ mem,
                                                     float* __restrict__ out) {
  __shared__ float Wts[O2_BK][O2_BM];
  __shared__ float Wns[O2_BK][O2_BM];
  __shared__ float Ms[O2_BK][O2_BN];
  const int tid = threadIdx.x;
  const int bm0 = blockIdx.y * O2_BM;
  const int bn0 = blockIdx.x * O2_BN;
  const int tm = tid >> 4, tn = tid & 15;
  float at[4][4] = {}, an[4][4] = {};
  for (int k0 = 0; k0 < MSLOTS; k0 += O2_BK) {
#pragma unroll
    for (int it = 0; it < 2; ++it) {
      int i = tid + it * 256;
      int row = i >> 3, c4 = i & 7;
      int gk = k0 + c4 * 4;
      float4 vt = make_float4(0.f, 0.f, 0.f, 0.f), vn = vt;
      if (gk < MSLOTS) {
        vt = *reinterpret_cast<const float4*>(&wt [(size_t)(bm0 + row) * MSLOTS + gk]);
        vn = *reinterpret_cast<const float4*>(&wnt[(size_t)(bm0 + row) * MSLOTS + gk]);
      }
      Wts[c4 * 4 + 0][row] = vt.x; Wts[c4 * 4 + 1][row] = vt.y;
      Wts[c4 * 4 + 2][row] = vt.z; Wts[c4 * 4 + 3][row] = vt.w;
      Wns[c4 * 4 + 0][row] = vn.x; Wns[c4 * 4 + 1][row] = vn.y;
      Wns[c4 * 4 + 2][row] = vn.z; Wns[c4 * 4 + 3][row] = vn.w;
    }
#pragma unroll
    for (int it = 0; it < 2; ++it) {
      int i = tid + it * 256;
      int row = i >> 4, c4 = i & 15;
      int gk = k0 + row;
      float4 v = make_float4(0.f, 0.f, 0.f, 0.f);
      if (gk < MSLOTS)
        v = *reinterpret_cast<const float4*>(&mem[(size_t)gk * FDIM + bn0 + c4 * 4]);
      *reinterpret_cast<float4*>(&Ms[row][c4 * 4]) = v;
    }
    __syncthreads();
#pragma unroll
    for (int kk = 0; kk < O2_BK; ++kk) {
      const float* tp = &Wts[kk][tm * 4];
      const float* np = &Wns[kk][tm * 4];
      const float* bp = &Ms[kk][tn * 4];
      float b0 = bp[0], b1 = bp[1], b2 = bp[2], b3 = bp[3];
#pragma unroll
      for (int i = 0; i < 4; ++i) {
        float a = tp[i], cn = np[i];
        at[i][0] = fmaf(a,  b0, at[i][0]); at[i][1] = fmaf(a,  b1, at[i][1]);
        at[i][2] = fmaf(a,  b2, at[i][2]); at[i][3] = fmaf(a,  b3, at[i][3]);
        an[i][0] = fmaf(cn, b0, an[i][0]); an[i][1] = fmaf(cn, b1, an[i][1]);
        an[i][2] = fmaf(cn, b2, an[i][2]); an[i][3] = fmaf(cn, b3, an[i][3]);
      }
    }
    __syncthreads();
  }
  float* outt = out;
  float* outn = out + (size_t)BATCH * FDIM;
#pragma unroll
  for (int i = 0; i < 4; ++i) {
    size_t off = (size_t)(bm0 + tm * 4 + i) * FDIM + bn0 + tn * 4;
    *reinterpret_cast<float4*>(&outt[off]) = make_float4(at[i][0], at[i][1], at[i][2], at[i][3]);
    *reinterpret_cast<float4*>(&outn[off]) = make_float4(an[i][0], an[i][1], an[i][2], an[i][3]);
  }
}

// ======================= host =======================
extern "C" void kernel_launch(void* const* d_in, const int* in_sizes, int n_in,
                              void* d_out, int out_size, void* d_ws, size_t ws_size,
                              hipStream_t stream) {
  const float* z      = (const float*)d_in[0];
  const int*   labels = (const int*)d_in[1];
  const float* mem    = (const float*)d_in[2];
  float* out = (float*)d_out;
  char*  wsb = (char*)d_ws;

  // new-path workspace layout (bytes)
  constexpr size_t NM_B   = 0;
  constexpr size_t NZ_B   = 8192;
  constexpr size_t ZB_B   = 16384;
  constexpr size_t MB_B   = ZB_B + (size_t)BATCH * FDIM * 2;
  constexpr size_t MT_B   = MB_B + (size_t)MPAD * FDIM * 2;
  constexpr size_t WTB_B  = MT_B + (size_t)FDIM * MPAD * 2;
  constexpr size_t WNB_B  = WTB_B + (size_t)BATCH * MPAD * 2;
  constexpr size_t PART_B = WNB_B + (size_t)BATCH * MPAD * 2;
  constexpr size_t ENT_B  = PART_B + (size_t)SPLITK * BATCH * MPAD * 4;
  constexpr size_t NEED   = ENT_B + 2048;

  if (ws_size >= NEED) {
    float* nm = (float*)(wsb + NM_B);
    float* nz = (float*)(wsb + NZ_B);
    unsigned short* zb = (unsigned short*)(wsb + ZB_B);
    unsigned short* mb = (unsigned short*)(wsb + MB_B);
    unsigned short* mt = (unsigned short*)(wsb + MT_B);
    unsigned short* wt = (unsigned short*)(wsb + WTB_B);
    unsigned short* wn = (unsigned short*)(wsb + WNB_B);
    float* part  = (float*)(wsb + PART_B);
    float* ent   = (float*)(wsb + ENT_B);

    convert_stream_kernel<<<(MPAD + BATCH) / 2, 256, 0, stream>>>(z, mem, zb, mb, nm, nz);
    transpose_kernel<<<dim3(FDIM / TR_F, MPAD / TR_M), 256, 0, stream>>>(mb, mt);
    gemm1_mfma<<<dim3(MPAD / G1_BN, BATCH / G1_BM, SPLITK), 256, 0, stream>>>(zb, mb, part);
    softmax2_kernel<<<BATCH, 256, 0, stream>>>(part, nz, nm, labels, wt, wn, ent);
    gemm23_mfma<<<dim3(FDIM / G2_BN, BATCH / G2_BM), 512, 0, stream>>>(wt, wn, mt, out);
    entreduce_kernel<<<1, 256, 0, stream>>>(ent, out);
  } else {
    float* ws    = (float*)d_ws;
    float* nm    = ws + NM_OFF;
    float* nzv   = ws + NZ_OFF;
    float* logit = ws + LOGIT_OFF;
    float* wt    = ws + WT_OFF;
    float* wnt   = ws + WNT_OFF;
    float* ent   = ws + ENT_OFF;

    rownorm_kernel<<<MSLOTS, 256, 0, stream>>>(mem, nm, FDIM);
    rownorm_kernel<<<BATCH, 256, 0, stream>>>(z, nzv, FDIM);
    gemm1_kernel<<<dim3((MSLOTS + O1_BN - 1) / O1_BN, BATCH / O1_BM), 256, 0, stream>>>(
        z, mem, nzv, nm, logit);
    softmax_kernel<<<BATCH, 256, 0, stream>>>(logit, labels, wt, wnt, ent);
    gemm23_kernel<<<dim3(FDIM / O2_BN, BATCH / O2_BM), 256, 0, stream>>>(wt, wnt, mem, out);
    entreduce_kernel<<<1, 256, 0, stream>>>(ent, out);
  }
}

// Round 8
// 153.828 us; speedup vs baseline: 1.0150x; 1.0150x over previous
//
#include <hip/hip_runtime.h>
#include <math.h>

#define BATCH 256
#define FDIM 16384
#define MSLOTS 2000
#define MPAD 2048
#define NCLS 10
#define MPC 200   // memories per class

static constexpr float THRESH = 2e-4f;
static constexpr float ENTC   = 2e-4f;
static constexpr float CEPS   = 1e-8f;
static constexpr float LEPS   = 1e-12f;

using bf16x8 = __attribute__((ext_vector_type(8))) short;
using f32x4  = __attribute__((ext_vector_type(4))) float;
using us8    = __attribute__((ext_vector_type(8))) unsigned short;

__device__ __forceinline__ unsigned short f2bf(float f) {
  unsigned u = __float_as_uint(f);
  unsigned r = u + 0x7fffu + ((u >> 16) & 1u);
  return (unsigned short)(r >> 16);
}

__device__ __forceinline__ void gload_lds16(const unsigned short* g, unsigned short* l) {
  __builtin_amdgcn_global_load_lds(
      (const __attribute__((address_space(1))) void*)g,
      (__attribute__((address_space(3))) void*)l, 16, 0, 0);
}

__device__ __forceinline__ float waveReduceSum(float v) {
#pragma unroll
  for (int o = 32; o > 0; o >>= 1) v += __shfl_xor(v, o);
  return v;
}
__device__ __forceinline__ float waveReduceMax(float v) {
#pragma unroll
  for (int o = 32; o > 0; o >>= 1) v = fmaxf(v, __shfl_xor(v, o));
  return v;
}

// ======================= bf16 MFMA PATH =======================

// ---- max-parallel streaming convert: one QUARTER-row (4096 fp32) per block ----
// 9216 blocks. rows 0..MPAD-1 -> mem (tail zero), rows MPAD.. -> z.
// Norm partials: npart[row*4 + q] = sum of squares of that quarter.
__global__ __launch_bounds__(256) void convert_stream_kernel(
    const float* __restrict__ z, const float* __restrict__ mem,
    unsigned short* __restrict__ zb, unsigned short* __restrict__ mb,
    float* __restrict__ npart) {
  const int tid = threadIdx.x;
  const int u = blockIdx.x;
  const int row = u >> 2, q = u & 3;
  const bool isMem = (row < MPAD);
  const int base = q * 4096;   // float offset within row
  unsigned short* orow = (isMem ? (mb + (size_t)row * FDIM)
                                : (zb + (size_t)(row - MPAD) * FDIM)) + base;
  if (isMem && row >= MSLOTS) {   // zero tail rows
    const uint2 zed = make_uint2(0u, 0u);
#pragma unroll
    for (int j = 0; j < 4; ++j)
      *reinterpret_cast<uint2*>(&orow[(j * 256 + tid) * 4]) = zed;
    if (tid == 0) npart[row * 4 + q] = 0.25f;   // norm finalizes to 1.0
    return;
  }
  const float* srow = (isMem ? (mem + (size_t)row * FDIM)
                             : (z + (size_t)(row - MPAD) * FDIM)) + base;
  float s = 0.f;
#pragma unroll
  for (int j = 0; j < 4; ++j) {
    const int off = (j * 256 + tid) * 4;   // lane-contiguous 16B per instr
    float4 v = *reinterpret_cast<const float4*>(&srow[off]);
    s = fmaf(v.x, v.x, fmaf(v.y, v.y, fmaf(v.z, v.z, fmaf(v.w, v.w, s))));
    uint2 o;
    o.x = ((unsigned)f2bf(v.y) << 16) | f2bf(v.x);
    o.y = ((unsigned)f2bf(v.w) << 16) | f2bf(v.z);
    *reinterpret_cast<uint2*>(&orow[off]) = o;
  }
  s = waveReduceSum(s);
  __shared__ float red[4];
  if ((tid & 63) == 0) red[tid >> 6] = s;
  __syncthreads();
  if (tid == 0) npart[row * 4 + q] = red[0] + red[1] + red[2] + red[3];
}

// ---- finalize norms: nm[0..2047], nz[0..255]; 36 blocks x 64 threads ----
__global__ __launch_bounds__(64) void normfin_kernel(const float* __restrict__ npart,
                                                     float* __restrict__ nm,
                                                     float* __restrict__ nz) {
  const int row = blockIdx.x * 64 + threadIdx.x;
  const float* p = npart + row * 4;
  float v = sqrtf(p[0] + p[1] + p[2] + p[3]);
  if (row < MPAD) nm[row] = v;
  else            nz[row - MPAD] = v;
}

// ---- standalone transpose mb[m][f] -> mt[f][m], 128m x 64f tiles ----
#define TR_M 128
#define TR_F 64
__global__ __launch_bounds__(256) void transpose_kernel(const unsigned short* __restrict__ mb,
                                                        unsigned short* __restrict__ mt) {
  __shared__ unsigned int P[TR_M * 34];   // row stride 34 u32 = 136 B
  const int tid = threadIdx.x;
  const int f0 = blockIdx.x * TR_F;
  const int m0 = blockIdx.y * TR_M;
#pragma unroll
  for (int it = 0; it < 4; ++it) {
    const int r = (tid >> 3) + it * 32;   // 0..127
    const int c8 = tid & 7;               // 16B chunk -> quads 2c8, 2c8+1
    const uint4 v = *reinterpret_cast<const uint4*>(
        &mb[(size_t)(m0 + r) * FDIM + f0 + c8 * 8]);
    const int x = (r >> 1) & 15;
    *reinterpret_cast<uint2*>(&P[r * 34 + 2 * ((2 * c8) ^ x)])     = make_uint2(v.x, v.y);
    *reinterpret_cast<uint2*>(&P[r * 34 + 2 * ((2 * c8 + 1) ^ x)]) = make_uint2(v.z, v.w);
  }
  __syncthreads();
#pragma unroll
  for (int half = 0; half < 2; ++half) {
    const int h = tid & 15;               // m-octet 0..15
    const int fp = (tid >> 4) + half * 16;  // f-pair 0..31
    unsigned p[8];
#pragma unroll
    for (int s = 0; s < 8; ++s) {
      const int m = h * 8 + s;
      const int col = fp ^ ((((m >> 1) & 15)) << 1);
      p[s] = P[m * 34 + col];
    }
    unsigned lo[4], hi[4];
#pragma unroll
    for (int t = 0; t < 4; ++t) {
      const unsigned p0 = p[2 * t], p1 = p[2 * t + 1];
      lo[t] = (p1 << 16) | (p0 & 0xFFFFu);         // f = 2*fp
      hi[t] = (p1 & 0xFFFF0000u) | (p0 >> 16);     // f = 2*fp+1
    }
    const size_t base = (size_t)(f0 + 2 * fp) * MPAD + m0 + h * 8;
    *reinterpret_cast<uint4*>(&mt[base])        = make_uint4(lo[0], lo[1], lo[2], lo[3]);
    *reinterpret_cast<uint4*>(&mt[base + MPAD]) = make_uint4(hi[0], hi[1], hi[2], hi[3]);
  }
}

// ---- GEMM1 (MFMA): partial[s][b][m] = sum_k z_bf16[b][k] * mem_bf16[m][k] ----
#define G1_BM 128
#define G1_BN 64
#define G1_BK 64
#define SPLITK 8
#define KCHUNK (FDIM / SPLITK)   // 2048

__global__ __launch_bounds__(256, 2) void gemm1_mfma(const unsigned short* __restrict__ zb,
                                                     const unsigned short* __restrict__ mb,
                                                     float* __restrict__ part) {
  __shared__ unsigned short As[G1_BM * G1_BK];  // rows of 64 bf16 (128 B), slot-swizzled
  __shared__ unsigned short Bs[G1_BN * G1_BK];
  const int tid = threadIdx.x;
  const int lane = tid & 63, wid = tid >> 6;
  const int bn0 = blockIdx.x * G1_BN;
  const int bm0 = blockIdx.y * G1_BM;
  const int kbase = blockIdx.z * KCHUNK;
  const int wr = wid >> 1, wc = wid & 1;  // wave tile 64x32
  const int l8 = lane >> 3, l7 = lane & 7;
  const int r16 = lane & 15, klane = lane >> 4;

  f32x4 acc[4][2] = {};

  for (int kt = 0; kt < KCHUNK; kt += G1_BK) {
    const int kg = kbase + kt;
#pragma unroll
    for (int it = 0; it < 4; ++it) {
      int c = wid + it * 4;
      int r = c * 8 + l8;
      int src = (l7 ^ (r & 7)) << 3;
      gload_lds16(&zb[(size_t)(bm0 + r) * FDIM + kg + src], &As[c * 512]);
    }
#pragma unroll
    for (int it = 0; it < 2; ++it) {
      int c = wid + it * 4;
      int r = c * 8 + l8;
      int src = (l7 ^ (r & 7)) << 3;
      gload_lds16(&mb[(size_t)(bn0 + r) * FDIM + kg + src], &Bs[c * 512]);
    }
    __syncthreads();
#pragma unroll
    for (int s = 0; s < 2; ++s) {
      bf16x8 a[4], bb[2];
#pragma unroll
      for (int i = 0; i < 4; ++i) {
        int r = wr * 64 + i * 16 + r16;
        int p = (s * 4 + klane) ^ (r & 7);
        a[i] = *reinterpret_cast<const bf16x8*>(&As[r * 64 + p * 8]);
      }
#pragma unroll
      for (int j = 0; j < 2; ++j) {
        int r = wc * 32 + j * 16 + r16;
        int p = (s * 4 + klane) ^ (r & 7);
        bb[j] = *reinterpret_cast<const bf16x8*>(&Bs[r * 64 + p * 8]);
      }
#pragma unroll
      for (int i = 0; i < 4; ++i)
#pragma unroll
        for (int j = 0; j < 2; ++j)
          acc[i][j] = __builtin_amdgcn_mfma_f32_16x16x32_bf16(a[i], bb[j], acc[i][j], 0, 0, 0);
    }
    __syncthreads();
  }
  const int rgrp = lane >> 4;
  float* pbase = part + (size_t)blockIdx.z * BATCH * MPAD;
#pragma unroll
  for (int i = 0; i < 4; ++i)
#pragma unroll
    for (int j = 0; j < 2; ++j)
#pragma unroll
      for (int rg = 0; rg < 4; ++rg) {
        int row = bm0 + wr * 64 + i * 16 + rgrp * 4 + rg;
        int col = bn0 + wc * 32 + j * 16 + r16;
        pbase[(size_t)row * MPAD + col] = acc[i][j][rg];
      }
}

// ---- softmax: fuse split-K reduce + norm divide; write bf16 w_t / w_nt; entropy fp32 ----
__global__ __launch_bounds__(256) void softmax2_kernel(const float* __restrict__ part,
                                                       const float* __restrict__ nzv,
                                                       const float* __restrict__ nmv,
                                                       const int* __restrict__ labels,
                                                       unsigned short* __restrict__ wt,
                                                       unsigned short* __restrict__ wn,
                                                       float* __restrict__ ent) {
  const int b = blockIdx.x, tid = threadIdx.x;
  __shared__ float sh[MSLOTS];
  __shared__ float red[4], red2[4];
  const float nzb = nzv[b];
  float mx = -3.4e38f;
  for (int m = tid; m < MSLOTS; m += 256) {
    float s = 0.f;
#pragma unroll
    for (int sp = 0; sp < SPLITK; ++sp)
      s += part[((size_t)sp * BATCH + b) * MPAD + m];
    float v = s / fmaxf(nzb * nmv[m], CEPS);
    sh[m] = v; mx = fmaxf(mx, v);
  }
  mx = waveReduceMax(mx);
  if ((tid & 63) == 0) red[tid >> 6] = mx;
  __syncthreads();
  mx = fmaxf(fmaxf(red[0], red[1]), fmaxf(red[2], red[3]));
  __syncthreads();

  float s = 0.f;
  for (int m = tid; m < MSLOTS; m += 256) {
    float e = expf(sh[m] - mx); sh[m] = e; s += e;
  }
  s = waveReduceSum(s);
  if ((tid & 63) == 0) red[tid >> 6] = s;
  __syncthreads();
  s = red[0] + red[1] + red[2] + red[3];
  __syncthreads();

  const float inv = 1.f / s;
  const int c = labels[b];
  const int t0 = c * MPC, t1 = t0 + MPC;
  float st = 0.f, sn = 0.f;
  for (int m = tid; m < MSLOTS; m += 256) {
    float w = sh[m] * inv;
    float k = (w > THRESH) ? w : 0.f;
    sh[m] = k;
    bool tgt = (m >= t0) && (m < t1);
    st += tgt ? k : 0.f;
    sn += tgt ? 0.f : k;
  }
  st = waveReduceSum(st); sn = waveReduceSum(sn);
  if ((tid & 63) == 0) { red[tid >> 6] = st; red2[tid >> 6] = sn; }
  __syncthreads();
  st = red[0] + red[1] + red[2] + red[3];
  sn = red2[0] + red2[1] + red2[2] + red2[3];
  __syncthreads();

  const float rt = 1.f / st, rn = 1.f / sn;
  float et = 0.f, en = 0.f;
  unsigned short* wtr = wt + (size_t)b * MPAD;
  unsigned short* wnr = wn + (size_t)b * MPAD;
  for (int m = tid; m < MPAD; m += 256) {
    float a = 0.f, cn = 0.f;
    if (m < MSLOTS) {
      float k = sh[m];
      bool tgt = (m >= t0) && (m < t1);
      a  = tgt ? k * rt : 0.f;
      cn = tgt ? 0.f : k * rn;
      et -= a  * logf(a  + LEPS);
      en -= cn * logf(cn + LEPS);
    }
    wtr[m] = f2bf(a);
    wnr[m] = f2bf(cn);
  }
  et = waveReduceSum(et); en = waveReduceSum(en);
  if ((tid & 63) == 0) { red[tid >> 6] = et; red2[tid >> 6] = en; }
  __syncthreads();
  if (tid == 0) {
    ent[b]         = red[0] + red[1] + red[2] + red[3];
    ent[BATCH + b] = red2[0] + red2[1] + red2[2] + red2[3];
  }
}

// ---- GEMM2+3 (MFMA, fused dual accumulator): z_hat = w @ mem via memT ----
#define G2_BM 128
#define G2_BN 128
#define G2_BK 64

__global__ __launch_bounds__(512, 2) void gemm23_mfma(const unsigned short* __restrict__ wt,
                                                      const unsigned short* __restrict__ wn,
                                                      const unsigned short* __restrict__ mt,
                                                      float* __restrict__ out) {
  __shared__ unsigned short At[G2_BM * G2_BK];
  __shared__ unsigned short An[G2_BM * G2_BK];
  __shared__ unsigned short Bs[G2_BN * G2_BK];
  const int tid = threadIdx.x, lane = tid & 63, wid = tid >> 6;
  const int bn0 = blockIdx.x * G2_BN;  // f
  const int bm0 = blockIdx.y * G2_BM;  // batch
  const int wr = wid >> 2, wc = wid & 3;  // 2x4 waves, each 64x32
  const int l8 = lane >> 3, l7 = lane & 7;
  const int r16 = lane & 15, klane = lane >> 4;

  f32x4 acct[4][2] = {}, accn[4][2] = {};

  for (int k0 = 0; k0 < MPAD; k0 += G2_BK) {
#pragma unroll
    for (int it = 0; it < 2; ++it) {
      int c = wid + it * 8;  // 16 chunks over 8 waves
      int r = c * 8 + l8;
      int src = (l7 ^ (r & 7)) << 3;
      gload_lds16(&wt[(size_t)(bm0 + r) * MPAD + k0 + src], &At[c * 512]);
      gload_lds16(&wn[(size_t)(bm0 + r) * MPAD + k0 + src], &An[c * 512]);
      gload_lds16(&mt[(size_t)(bn0 + r) * MPAD + k0 + src], &Bs[c * 512]);
    }
    __syncthreads();
#pragma unroll
    for (int s = 0; s < 2; ++s) {
      bf16x8 at[4], an[4], bb[2];
#pragma unroll
      for (int i = 0; i < 4; ++i) {
        int r = wr * 64 + i * 16 + r16;
        int p = (s * 4 + klane) ^ (r & 7);
        at[i] = *reinterpret_cast<const bf16x8*>(&At[r * 64 + p * 8]);
        an[i] = *reinterpret_cast<const bf16x8*>(&An[r * 64 + p * 8]);
      }
#pragma unroll
      for (int j = 0; j < 2; ++j) {
        int r = wc * 32 + j * 16 + r16;
        int p = (s * 4 + klane) ^ (r & 7);
        bb[j] = *reinterpret_cast<const bf16x8*>(&Bs[r * 64 + p * 8]);
      }
#pragma unroll
      for (int i = 0; i < 4; ++i)
#pragma unroll
        for (int j = 0; j < 2; ++j) {
          acct[i][j] = __builtin_amdgcn_mfma_f32_16x16x32_bf16(at[i], bb[j], acct[i][j], 0, 0, 0);
          accn[i][j] = __builtin_amdgcn_mfma_f32_16x16x32_bf16(an[i], bb[j], accn[i][j], 0, 0, 0);
        }
    }
    __syncthreads();
  }
  float* outn = out + (size_t)BATCH * FDIM;
  const int rgrp = lane >> 4;
#pragma unroll
  for (int i = 0; i < 4; ++i)
#pragma unroll
    for (int j = 0; j < 2; ++j)
#pragma unroll
      for (int rg = 0; rg < 4; ++rg) {
        size_t off = (size_t)(bm0 + wr * 64 + i * 16 + rgrp * 4 + rg) * FDIM
                   + bn0 + wc * 32 + j * 16 + r16;
        out[off]  = acct[i][j][rg];
        outn[off] = accn[i][j][rg];
      }
}

// ---- entropy final reduce ----
__global__ __launch_bounds__(256) void entreduce_kernel(const float* __restrict__ ent,
                                                        float* __restrict__ out) {
  const int tid = threadIdx.x;
  float v = ent[tid];
  float u = ent[BATCH + tid];
  v = waveReduceSum(v); u = waveReduceSum(u);
  __shared__ float r1[4], r2[4];
  if ((tid & 63) == 0) { r1[tid >> 6] = v; r2[tid >> 6] = u; }
  __syncthreads();
  if (tid == 0) {
    out[(size_t)2 * BATCH * FDIM]     = ENTC * (r1[0] + r1[1] + r1[2] + r1[3]);
    out[(size_t)2 * BATCH * FDIM + 1] = ENTC * (r2[0] + r2[1] + r2[2] + r2[3]);
  }
}

// ======================= OLD fp32 FALLBACK PATH =======================
#define NM_OFF    0
#define NZ_OFF    2048
#define LOGIT_OFF 4096
#define WT_OFF    (LOGIT_OFF + 512000)
#define WNT_OFF   (WT_OFF + 512000)
#define ENT_OFF   (WNT_OFF + 512000)

__global__ __launch_bounds__(256) void rownorm_kernel(const float* __restrict__ x,
                                                      float* __restrict__ out, int cols) {
  const int r = blockIdx.x;
  const float4* xr = reinterpret_cast<const float4*>(x) + (size_t)r * (cols >> 2);
  const int n4 = cols >> 2;
  float s = 0.f;
  for (int i = threadIdx.x; i < n4; i += 256) {
    float4 v = xr[i];
    s = fmaf(v.x, v.x, s); s = fmaf(v.y, v.y, s);
    s = fmaf(v.z, v.z, s); s = fmaf(v.w, v.w, s);
  }
  s = waveReduceSum(s);
  __shared__ float red[4];
  if ((threadIdx.x & 63) == 0) red[threadIdx.x >> 6] = s;
  __syncthreads();
  if (threadIdx.x == 0) out[r] = sqrtf(red[0] + red[1] + red[2] + red[3]);
}

#define O1_BM 64
#define O1_BN 32
#define O1_BK 64
__global__ __launch_bounds__(256) void gemm1_kernel(const float* __restrict__ z,
                                                    const float* __restrict__ mem,
                                                    const float* __restrict__ nzv,
                                                    const float* __restrict__ nmv,
                                                    float* __restrict__ logit) {
  __shared__ float As[O1_BK][O1_BM];
  __shared__ float Bs[O1_BK][O1_BN];
  const int tid = threadIdx.x;
  const int bm0 = blockIdx.y * O1_BM;
  const int bn0 = blockIdx.x * O1_BN;
  const int tm = tid >> 4, tn = tid & 15;
  float acc[4][2] = {};
  for (int k0 = 0; k0 < FDIM; k0 += O1_BK) {
#pragma unroll
    for (int it = 0; it < 4; ++it) {
      int i = tid + it * 256;
      int row = i >> 4, c4 = i & 15;
      float4 v = *reinterpret_cast<const float4*>(&z[(size_t)(bm0 + row) * FDIM + k0 + c4 * 4]);
      As[c4 * 4 + 0][row] = v.x; As[c4 * 4 + 1][row] = v.y;
      As[c4 * 4 + 2][row] = v.z; As[c4 * 4 + 3][row] = v.w;
    }
#pragma unroll
    for (int it = 0; it < 2; ++it) {
      int i = tid + it * 256;
      int row = i >> 4, c4 = i & 15;
      int gm = bn0 + row;
      float4 v = make_float4(0.f, 0.f, 0.f, 0.f);
      if (gm < MSLOTS)
        v = *reinterpret_cast<const float4*>(&mem[(size_t)gm * FDIM + k0 + c4 * 4]);
      Bs[c4 * 4 + 0][row] = v.x; Bs[c4 * 4 + 1][row] = v.y;
      Bs[c4 * 4 + 2][row] = v.z; Bs[c4 * 4 + 3][row] = v.w;
    }
    __syncthreads();
#pragma unroll
    for (int kk = 0; kk < O1_BK; ++kk) {
      const float* ap = &As[kk][tm * 4];
      const float* bp = &Bs[kk][tn * 2];
      float a0 = ap[0], a1 = ap[1], a2 = ap[2], a3 = ap[3];
      float b0 = bp[0], b1 = bp[1];
      acc[0][0] = fmaf(a0, b0, acc[0][0]); acc[0][1] = fmaf(a0, b1, acc[0][1]);
      acc[1][0] = fmaf(a1, b0, acc[1][0]); acc[1][1] = fmaf(a1, b1, acc[1][1]);
      acc[2][0] = fmaf(a2, b0, acc[2][0]); acc[2][1] = fmaf(a2, b1, acc[2][1]);
      acc[3][0] = fmaf(a3, b0, acc[3][0]); acc[3][1] = fmaf(a3, b1, acc[3][1]);
    }
    __syncthreads();
  }
  float nzr[4];
#pragma unroll
  for (int i = 0; i < 4; ++i) nzr[i] = nzv[bm0 + tm * 4 + i];
#pragma unroll
  for (int j = 0; j < 2; ++j) {
    int col = bn0 + tn * 2 + j;
    if (col < MSLOTS) {
      float nmr = nmv[col];
#pragma unroll
      for (int i = 0; i < 4; ++i)
        logit[(size_t)(bm0 + tm * 4 + i) * MSLOTS + col] = acc[i][j] / fmaxf(nzr[i] * nmr, CEPS);
    }
  }
}

__global__ __launch_bounds__(256) void softmax_kernel(const float* __restrict__ logit,
                                                      const int* __restrict__ labels,
                                                      float* __restrict__ wt,
                                                      float* __restrict__ wnt,
                                                      float* __restrict__ ent) {
  const int b = blockIdx.x;
  const int tid = threadIdx.x;
  __shared__ float sh[MSLOTS];
  __shared__ float red[4], red2[4];
  const float* lrow = logit + (size_t)b * MSLOTS;
  float mx = -3.4e38f;
  for (int m = tid; m < MSLOTS; m += 256) {
    float v = lrow[m]; sh[m] = v; mx = fmaxf(mx, v);
  }
  mx = waveReduceMax(mx);
  if ((tid & 63) == 0) red[tid >> 6] = mx;
  __syncthreads();
  mx = fmaxf(fmaxf(red[0], red[1]), fmaxf(red[2], red[3]));
  __syncthreads();
  float s = 0.f;
  for (int m = tid; m < MSLOTS; m += 256) {
    float e = expf(sh[m] - mx); sh[m] = e; s += e;
  }
  s = waveReduceSum(s);
  if ((tid & 63) == 0) red[tid >> 6] = s;
  __syncthreads();
  s = red[0] + red[1] + red[2] + red[3];
  __syncthreads();
  const float inv = 1.f / s;
  const int c = labels[b];
  const int t0 = c * MPC, t1 = t0 + MPC;
  float st = 0.f, sn = 0.f;
  for (int m = tid; m < MSLOTS; m += 256) {
    float w = sh[m] * inv;
    float k = (w > THRESH) ? w : 0.f;
    sh[m] = k;
    bool tgt = (m >= t0) && (m < t1);
    st += tgt ? k : 0.f;
    sn += tgt ? 0.f : k;
  }
  st = waveReduceSum(st); sn = waveReduceSum(sn);
  if ((tid & 63) == 0) { red[tid >> 6] = st; red2[tid >> 6] = sn; }
  __syncthreads();
  st = red[0] + red[1] + red[2] + red[3];
  sn = red2[0] + red2[1] + red2[2] + red2[3];
  __syncthreads();
  const float rt = 1.f / st, rn = 1.f / sn;
  float et = 0.f, en = 0.f;
  float* wtr = wt + (size_t)b * MSLOTS;
  float* wnr = wnt + (size_t)b * MSLOTS;
  for (int m = tid; m < MSLOTS; m += 256) {
    float k = sh[m];
    bool tgt = (m >= t0) && (m < t1);
    float a  = tgt ? k * rt : 0.f;
    float cn = tgt ? 0.f : k * rn;
    wtr[m] = a;
    wnr[m] = cn;
    et -= a  * logf(a  + LEPS);
    en -= cn * logf(cn + LEPS);
  }
  et = waveReduceSum(et); en = waveReduceSum(en);
  if ((tid & 63) == 0) { red[tid >> 6] = et; red2[tid >> 6] = en; }
  __syncthreads();
  if (tid == 0) {
    ent[b]         = red[0] + red[1] + red[2] + red[3];
    ent[BATCH + b] = red2[0] + red2[1] + red2[2] + red2[3];
  }
}

#define O2_BM 64
#define O2_BN 64
#define O2_BK 32
__global__ __launch_bounds__(256) void gemm23_kernel(const float* __restrict__ wt,
                                                     const float* __restrict__ wnt,
                                                     const float* __restrict__ mem,
                                                     float* __restrict__ out) {
  __shared__ float Wts[O2_BK][O2_BM];
  __shared__ float Wns[O2_BK][O2_BM];
  __shared__ float Ms[O2_BK][O2_BN];
  const int tid = threadIdx.x;
  const int bm0 = blockIdx.y * O2_BM;
  const int bn0 = blockIdx.x * O2_BN;
  const int tm = tid >> 4, tn = tid & 15;
  float at[4][4] = {}, an[4][4] = {};
  for (int k0 = 0; k0 < MSLOTS; k0 += O2_BK) {
#pragma unroll
    for (int it = 0; it < 2; ++it) {
      int i = tid + it * 256;
      int row = i >> 3, c4 = i & 7;
      int gk = k0 + c4 * 4;
      float4 vt = make_float4(0.f, 0.f, 0.f, 0.f), vn = vt;
      if (gk < MSLOTS) {
        vt = *reinterpret_cast<const float4*>(&wt [(size_t)(bm0 + row) * MSLOTS + gk]);
        vn = *reinterpret_cast<const float4*>(&wnt[(size_t)(bm0 + row) * MSLOTS + gk]);
      }
      Wts[c4 * 4 + 0][row] = vt.x; Wts[c4 * 4 + 1][row] = vt.y;
      Wts[c4 * 4 + 2][row] = vt.z; Wts[c4 * 4 + 3][row] = vt.w;
      Wns[c4 * 4 + 0][row] = vn.x; Wns[c4 * 4 + 1][row] = vn.y;
      Wns[c4 * 4 + 2][row] = vn.z; Wns[c4 * 4 + 3][row] = vn.w;
    }
#pragma unroll
    for (int it = 0; it < 2; ++it) {
      int i = tid + it * 256;
      int row = i >> 4, c4 = i & 15;
      int gk = k0 + row;
      float4 v = make_float4(0.f, 0.f, 0.f, 0.f);
      if (gk < MSLOTS)
        v = *reinterpret_cast<const float4*>(&mem[(size_t)gk * FDIM + bn0 + c4 * 4]);
      *reinterpret_cast<float4*>(&Ms[row][c4 * 4]) = v;
    }
    __syncthreads();
#pragma unroll
    for (int kk = 0; kk < O2_BK; ++kk) {
      const float* tp = &Wts[kk][tm * 4];
      const float* np = &Wns[kk][tm * 4];
      const float* bp = &Ms[kk][tn * 4];
      float b0 = bp[0], b1 = bp[1], b2 = bp[2], b3 = bp[3];
#pragma unroll
      for (int i = 0; i < 4; ++i) {
        float a = tp[i], cn = np[i];
        at[i][0] = fmaf(a,  b0, at[i][0]); at[i][1] = fmaf(a,  b1, at[i][1]);
        at[i][2] = fmaf(a,  b2, at[i][2]); at[i][3] = fmaf(a,  b3, at[i][3]);
        an[i][0] = fmaf(cn, b0, an[i][0]); an[i][1] = fmaf(cn, b1, an[i][1]);
        an[i][2] = fmaf(cn, b2, an[i][2]); an[i][3] = fmaf(cn, b3, an[i][3]);
      }
    }
    __syncthreads();
  }
  float* outt = out;
  float* outn = out + (size_t)BATCH * FDIM;
#pragma unroll
  for (int i = 0; i < 4; ++i) {
    size_t off = (size_t)(bm0 + tm * 4 + i) * FDIM + bn0 + tn * 4;
    *reinterpret_cast<float4*>(&outt[off]) = make_float4(at[i][0], at[i][1], at[i][2], at[i][3]);
    *reinterpret_cast<float4*>(&outn[off]) = make_float4(an[i][0], an[i][1], an[i][2], an[i][3]);
  }
}

// ======================= host =======================
extern "C" void kernel_launch(void* const* d_in, const int* in_sizes, int n_in,
                              void* d_out, int out_size, void* d_ws, size_t ws_size,
                              hipStream_t stream) {
  const float* z      = (const float*)d_in[0];
  const int*   labels = (const int*)d_in[1];
  const float* mem    = (const float*)d_in[2];
  float* out = (float*)d_out;
  char*  wsb = (char*)d_ws;

  // new-path workspace layout (bytes)
  constexpr size_t NM_B   = 0;
  constexpr size_t NZ_B   = 8192;
  constexpr size_t NP_B   = 16384;                               // 2304*4 floats = 36 KB
  constexpr size_t ZB_B   = NP_B + 40960;
  constexpr size_t MB_B   = ZB_B + (size_t)BATCH * FDIM * 2;
  constexpr size_t MT_B   = MB_B + (size_t)MPAD * FDIM * 2;
  constexpr size_t WTB_B  = MT_B + (size_t)FDIM * MPAD * 2;
  constexpr size_t WNB_B  = WTB_B + (size_t)BATCH * MPAD * 2;
  constexpr size_t PART_B = WNB_B + (size_t)BATCH * MPAD * 2;
  constexpr size_t ENT_B  = PART_B + (size_t)SPLITK * BATCH * MPAD * 4;
  constexpr size_t NEED   = ENT_B + 2048;

  if (ws_size >= NEED) {
    float* nm = (float*)(wsb + NM_B);
    float* nz = (float*)(wsb + NZ_B);
    float* npart = (float*)(wsb + NP_B);
    unsigned short* zb = (unsigned short*)(wsb + ZB_B);
    unsigned short* mb = (unsigned short*)(wsb + MB_B);
    unsigned short* mt = (unsigned short*)(wsb + MT_B);
    unsigned short* wt = (unsigned short*)(wsb + WTB_B);
    unsigned short* wn = (unsigned short*)(wsb + WNB_B);
    float* part  = (float*)(wsb + PART_B);
    float* ent   = (float*)(wsb + ENT_B);

    convert_stream_kernel<<<(MPAD + BATCH) * 4, 256, 0, stream>>>(z, mem, zb, mb, npart);
    normfin_kernel<<<(MPAD + BATCH) / 64, 64, 0, stream>>>(npart, nm, nz);
    transpose_kernel<<<dim3(FDIM / TR_F, MPAD / TR_M), 256, 0, stream>>>(mb, mt);
    gemm1_mfma<<<dim3(MPAD / G1_BN, BATCH / G1_BM, SPLITK), 256, 0, stream>>>(zb, mb, part);
    softmax2_kernel<<<BATCH, 256, 0, stream>>>(part, nz, nm, labels, wt, wn, ent);
    gemm23_mfma<<<dim3(FDIM / G2_BN, BATCH / G2_BM), 512, 0, stream>>>(wt, wn, mt, out);
    entreduce_kernel<<<1, 256, 0, stream>>>(ent, out);
  } else {
    float* ws    = (float*)d_ws;
    float* nm    = ws + NM_OFF;
    float* nzv   = ws + NZ_OFF;
    float* logit = ws + LOGIT_OFF;
    float* wt    = ws + WT_OFF;
    float* wnt   = ws + WNT_OFF;
    float* ent   = ws + ENT_OFF;

    rownorm_kernel<<<MSLOTS, 256, 0, stream>>>(mem, nm, FDIM);
    rownorm_kernel<<<BATCH, 256, 0, stream>>>(z, nzv, FDIM);
    gemm1_kernel<<<dim3((MSLOTS + O1_BN - 1) / O1_BN, BATCH / O1_BM), 256, 0, stream>>>(
        z, mem, nzv, nm, logit);
    softmax_kernel<<<BATCH, 256, 0, stream>>>(logit, labels, wt, wnt, ent);
    gemm23_kernel<<<dim3(FDIM / O2_BN, BATCH / O2_BM), 256, 0, stream>>>(wt, wnt, mem, out);
    entreduce_kernel<<<1, 256, 0, stream>>>(ent, out);
  }
}

// Round 9
// 153.345 us; speedup vs baseline: 1.0182x; 1.0032x over previous
//
#include <hip/hip_runtime.h>
#include <math.h>

#define BATCH 256
#define FDIM 16384
#define MSLOTS 2000
#define MPAD 2048
#define NCLS 10
#define MPC 200   // memories per class
#define NFB (FDIM / 64)   // 256 f-tiles

static constexpr float THRESH = 2e-4f;
static constexpr float ENTC   = 2e-4f;
static constexpr float CEPS   = 1e-8f;
static constexpr float LEPS   = 1e-12f;

using bf16x8 = __attribute__((ext_vector_type(8))) short;
using f32x4  = __attribute__((ext_vector_type(4))) float;
using us8    = __attribute__((ext_vector_type(8))) unsigned short;

__device__ __forceinline__ unsigned short f2bf(float f) {
  unsigned u = __float_as_uint(f);
  unsigned r = u + 0x7fffu + ((u >> 16) & 1u);
  return (unsigned short)(r >> 16);
}

__device__ __forceinline__ void gload_lds16(const unsigned short* g, unsigned short* l) {
  __builtin_amdgcn_global_load_lds(
      (const __attribute__((address_space(1))) void*)g,
      (__attribute__((address_space(3))) void*)l, 16, 0, 0);
}

__device__ __forceinline__ float waveReduceSum(float v) {
#pragma unroll
  for (int o = 32; o > 0; o >>= 1) v += __shfl_xor(v, o);
  return v;
}
__device__ __forceinline__ float waveReduceMax(float v) {
#pragma unroll
  for (int o = 32; o > 0; o >>= 1) v = fmaxf(v, __shfl_xor(v, o));
  return v;
}

// ======================= bf16 MFMA PATH =======================

// ---- fused convert (mem -> mb + mt, z -> zb) + register-accumulated norms ----
// (r4-proven version: the transpose hides inside the latency-bound d_in read.)
// grid: x = NFB (256 f-tiles), y = 36 row-tiles (0..31 mem, 32..35 z)
__global__ __launch_bounds__(256) void convert_all_kernel(
    const float* __restrict__ z, const float* __restrict__ mem,
    unsigned short* __restrict__ zb, unsigned short* __restrict__ mb,
    unsigned short* __restrict__ mt, float* __restrict__ npart) {
  __shared__ unsigned int P[64 * 34];   // 8704 B, rows padded to 34 u32
  __shared__ float rsum[64][17];        // norm partials, padded
  const int tid = threadIdx.x;
  const int f0 = blockIdx.x * 64;
  const int yt = blockIdx.y;
  const bool isMem = (yt < MPAD / 64);
  const int r0 = isMem ? yt * 64 : (yt - MPAD / 64) * 64;
  const float* src = isMem ? mem : z;
  unsigned short* dst = isMem ? mb : zb;

  const int q = tid & 15;        // f-quad (4 floats)
  const int mb0 = tid >> 4;      // base row 0..15

  // phase 1: read fp32, convert, write row-major bf16 from regs, stage packed LDS
#pragma unroll
  for (int it = 0; it < 4; ++it) {
    const int m = mb0 + it * 16;
    const int gr = r0 + m;
    float4 v = make_float4(0.f, 0.f, 0.f, 0.f);
    if (!isMem || gr < MSLOTS)
      v = *reinterpret_cast<const float4*>(&src[(size_t)gr * FDIM + f0 + q * 4]);
    rsum[m][q] = fmaf(v.x, v.x, fmaf(v.y, v.y, fmaf(v.z, v.z, v.w * v.w)));
    unsigned lo = ((unsigned)f2bf(v.y) << 16) | f2bf(v.x);
    unsigned hi = ((unsigned)f2bf(v.w) << 16) | f2bf(v.z);
    *reinterpret_cast<uint2*>(&dst[(size_t)gr * FDIM + f0 + q * 4]) = make_uint2(lo, hi);
    if (isMem) {
      const int x = (m >> 1) & 15;
      const int col = 2 * (q ^ x);           // even -> 8B aligned b64 write
      *reinterpret_cast<uint2*>(&P[m * 34 + col]) = make_uint2(lo, hi);
    }
  }
  __syncthreads();

  // phase 2 (mem only): packed transpose out of LDS -> mt[f][m]
  if (isMem) {
    const int h = tid & 7;       // m-octet
    const int j = tid >> 3;      // f-pair 0..31
    unsigned p[8];
#pragma unroll
    for (int s = 0; s < 8; ++s) {
      const int m = 8 * h + s;
      const int col = j ^ (((m >> 1) & 15) << 1);
      p[s] = P[m * 34 + col];
    }
    unsigned lo[4], hi[4];
#pragma unroll
    for (int t = 0; t < 4; ++t) {
      const unsigned p0 = p[2 * t], p1 = p[2 * t + 1];
      lo[t] = (p1 << 16) | (p0 & 0xFFFFu);          // f = 2j
      hi[t] = (p1 & 0xFFFF0000u) | (p0 >> 16);      // f = 2j+1
    }
    const size_t base0 = (size_t)(f0 + 2 * j) * MPAD + r0 + h * 8;
    *reinterpret_cast<uint4*>(&mt[base0])        = make_uint4(lo[0], lo[1], lo[2], lo[3]);
    *reinterpret_cast<uint4*>(&mt[base0 + MPAD]) = make_uint4(hi[0], hi[1], hi[2], hi[3]);
  }

  // norm partial reduce: 64 threads, one row each
  if (tid < 64) {
    float s = 0.f;
#pragma unroll
    for (int c = 0; c < 16; ++c) s += rsum[tid][c];
    const int row = isMem ? (r0 + tid) : (MPAD + r0 + tid);
    npart[(size_t)row * NFB + blockIdx.x] = s;
  }
}

// ---- finalize norms: nm[0..2047], nz[0..255] ----
__global__ __launch_bounds__(64) void normfin_kernel(const float* __restrict__ npart,
                                                     float* __restrict__ nm,
                                                     float* __restrict__ nz) {
  const int row = blockIdx.x;
  const int lane = threadIdx.x;
  const float* p = npart + (size_t)row * NFB;
  float s = 0.f;
#pragma unroll
  for (int k = 0; k < NFB / 64; ++k) s += p[lane + k * 64];
  s = waveReduceSum(s);
  if (lane == 0) {
    float v = sqrtf(s);
    if (row < MPAD) nm[row] = v;
    else            nz[row - MPAD] = v;
  }
}

// ---- GEMM1 (MFMA): partial[s][b][m] = sum_k z_bf16[b][k] * mem_bf16[m][k] ----
#define G1_BM 128
#define G1_BN 64
#define G1_BK 64
#define SPLITK 8
#define KCHUNK (FDIM / SPLITK)   // 2048

__global__ __launch_bounds__(256, 2) void gemm1_mfma(const unsigned short* __restrict__ zb,
                                                     const unsigned short* __restrict__ mb,
                                                     float* __restrict__ part) {
  __shared__ unsigned short As[G1_BM * G1_BK];  // rows of 64 bf16 (128 B), slot-swizzled
  __shared__ unsigned short Bs[G1_BN * G1_BK];
  const int tid = threadIdx.x;
  const int lane = tid & 63, wid = tid >> 6;
  const int bn0 = blockIdx.x * G1_BN;
  const int bm0 = blockIdx.y * G1_BM;
  const int kbase = blockIdx.z * KCHUNK;
  const int wr = wid >> 1, wc = wid & 1;  // wave tile 64x32
  const int l8 = lane >> 3, l7 = lane & 7;
  const int r16 = lane & 15, klane = lane >> 4;

  f32x4 acc[4][2] = {};

  for (int kt = 0; kt < KCHUNK; kt += G1_BK) {
    const int kg = kbase + kt;
#pragma unroll
    for (int it = 0; it < 4; ++it) {
      int c = wid + it * 4;
      int r = c * 8 + l8;
      int src = (l7 ^ (r & 7)) << 3;
      gload_lds16(&zb[(size_t)(bm0 + r) * FDIM + kg + src], &As[c * 512]);
    }
#pragma unroll
    for (int it = 0; it < 2; ++it) {
      int c = wid + it * 4;
      int r = c * 8 + l8;
      int src = (l7 ^ (r & 7)) << 3;
      gload_lds16(&mb[(size_t)(bn0 + r) * FDIM + kg + src], &Bs[c * 512]);
    }
    __syncthreads();
#pragma unroll
    for (int s = 0; s < 2; ++s) {
      bf16x8 a[4], bb[2];
#pragma unroll
      for (int i = 0; i < 4; ++i) {
        int r = wr * 64 + i * 16 + r16;
        int p = (s * 4 + klane) ^ (r & 7);
        a[i] = *reinterpret_cast<const bf16x8*>(&As[r * 64 + p * 8]);
      }
#pragma unroll
      for (int j = 0; j < 2; ++j) {
        int r = wc * 32 + j * 16 + r16;
        int p = (s * 4 + klane) ^ (r & 7);
        bb[j] = *reinterpret_cast<const bf16x8*>(&Bs[r * 64 + p * 8]);
      }
#pragma unroll
      for (int i = 0; i < 4; ++i)
#pragma unroll
        for (int j = 0; j < 2; ++j)
          acc[i][j] = __builtin_amdgcn_mfma_f32_16x16x32_bf16(a[i], bb[j], acc[i][j], 0, 0, 0);
    }
    __syncthreads();
  }
  const int rgrp = lane >> 4;
  float* pbase = part + (size_t)blockIdx.z * BATCH * MPAD;
#pragma unroll
  for (int i = 0; i < 4; ++i)
#pragma unroll
    for (int j = 0; j < 2; ++j)
#pragma unroll
      for (int rg = 0; rg < 4; ++rg) {
        int row = bm0 + wr * 64 + i * 16 + rgrp * 4 + rg;
        int col = bn0 + wc * 32 + j * 16 + r16;
        pbase[(size_t)row * MPAD + col] = acc[i][j][rg];
      }
}

// ---- softmax: fuse split-K reduce + norm divide; write bf16 w_t / w_nt; entropy fp32 ----
__global__ __launch_bounds__(256) void softmax2_kernel(const float* __restrict__ part,
                                                       const float* __restrict__ nzv,
                                                       const float* __restrict__ nmv,
                                                       const int* __restrict__ labels,
                                                       unsigned short* __restrict__ wt,
                                                       unsigned short* __restrict__ wn,
                                                       float* __restrict__ ent) {
  const int b = blockIdx.x, tid = threadIdx.x;
  __shared__ float sh[MSLOTS];
  __shared__ float red[4], red2[4];
  const float nzb = nzv[b];
  float mx = -3.4e38f;
  for (int m = tid; m < MSLOTS; m += 256) {
    float s = 0.f;
#pragma unroll
    for (int sp = 0; sp < SPLITK; ++sp)
      s += part[((size_t)sp * BATCH + b) * MPAD + m];
    float v = s / fmaxf(nzb * nmv[m], CEPS);
    sh[m] = v; mx = fmaxf(mx, v);
  }
  mx = waveReduceMax(mx);
  if ((tid & 63) == 0) red[tid >> 6] = mx;
  __syncthreads();
  mx = fmaxf(fmaxf(red[0], red[1]), fmaxf(red[2], red[3]));
  __syncthreads();

  float s = 0.f;
  for (int m = tid; m < MSLOTS; m += 256) {
    float e = expf(sh[m] - mx); sh[m] = e; s += e;
  }
  s = waveReduceSum(s);
  if ((tid & 63) == 0) red[tid >> 6] = s;
  __syncthreads();
  s = red[0] + red[1] + red[2] + red[3];
  __syncthreads();

  const float inv = 1.f / s;
  const int c = labels[b];
  const int t0 = c * MPC, t1 = t0 + MPC;
  float st = 0.f, sn = 0.f;
  for (int m = tid; m < MSLOTS; m += 256) {
    float w = sh[m] * inv;
    float k = (w > THRESH) ? w : 0.f;
    sh[m] = k;
    bool tgt = (m >= t0) && (m < t1);
    st += tgt ? k : 0.f;
    sn += tgt ? 0.f : k;
  }
  st = waveReduceSum(st); sn = waveReduceSum(sn);
  if ((tid & 63) == 0) { red[tid >> 6] = st; red2[tid >> 6] = sn; }
  __syncthreads();
  st = red[0] + red[1] + red[2] + red[3];
  sn = red2[0] + red2[1] + red2[2] + red2[3];
  __syncthreads();

  const float rt = 1.f / st, rn = 1.f / sn;
  float et = 0.f, en = 0.f;
  unsigned short* wtr = wt + (size_t)b * MPAD;
  unsigned short* wnr = wn + (size_t)b * MPAD;
  for (int m = tid; m < MPAD; m += 256) {
    float a = 0.f, cn = 0.f;
    if (m < MSLOTS) {
      float k = sh[m];
      bool tgt = (m >= t0) && (m < t1);
      a  = tgt ? k * rt : 0.f;
      cn = tgt ? 0.f : k * rn;
      et -= a  * logf(a  + LEPS);
      en -= cn * logf(cn + LEPS);
    }
    wtr[m] = f2bf(a);
    wnr[m] = f2bf(cn);
  }
  et = waveReduceSum(et); en = waveReduceSum(en);
  if ((tid & 63) == 0) { red[tid >> 6] = et; red2[tid >> 6] = en; }
  __syncthreads();
  if (tid == 0) {
    ent[b]         = red[0] + red[1] + red[2] + red[3];
    ent[BATCH + b] = red2[0] + red2[1] + red2[2] + red2[3];
  }
}

// ---- GEMM2+3 (MFMA, dual acc, DOUBLE-BUFFERED 2-phase) ----
// grid = 256 blocks = 1 block/CU: no inter-block overlap exists, so the
// stage-drain is fully exposed -> intra-block dbuf overlap is not redundant
// here (unlike m99/m100's 2-3 blocks/CU null regime). One barrier per K-step.
#define G2_BM 128
#define G2_BN 128
#define G2_BK 64
#define G2_NT (MPAD / G2_BK)   // 32

__global__ __launch_bounds__(512, 2) void gemm23_mfma(const unsigned short* __restrict__ wt,
                                                      const unsigned short* __restrict__ wn,
                                                      const unsigned short* __restrict__ mt,
                                                      float* __restrict__ out) {
  __shared__ unsigned short At[2][G2_BM * G2_BK];   // 2 x 16 KB
  __shared__ unsigned short An[2][G2_BM * G2_BK];   // 2 x 16 KB
  __shared__ unsigned short Bs[2][G2_BN * G2_BK];   // 2 x 16 KB  (96 KB total)
  const int tid = threadIdx.x, lane = tid & 63, wid = tid >> 6;
  const int bn0 = blockIdx.x * G2_BN;  // f
  const int bm0 = blockIdx.y * G2_BM;  // batch
  const int wr = wid >> 2, wc = wid & 3;  // 2x4 waves, each 64x32
  const int l8 = lane >> 3, l7 = lane & 7;
  const int r16 = lane & 15, klane = lane >> 4;

  f32x4 acct[4][2] = {}, accn[4][2] = {};

  // prologue: stage K-tile 0 into buffer 0
#pragma unroll
  for (int it = 0; it < 2; ++it) {
    int c = wid + it * 8;
    int r = c * 8 + l8;
    int src = (l7 ^ (r & 7)) << 3;
    gload_lds16(&wt[(size_t)(bm0 + r) * MPAD + src], &At[0][c * 512]);
    gload_lds16(&wn[(size_t)(bm0 + r) * MPAD + src], &An[0][c * 512]);
    gload_lds16(&mt[(size_t)(bn0 + r) * MPAD + src], &Bs[0][c * 512]);
  }
  __syncthreads();

  for (int kt = 0; kt < G2_NT; ++kt) {
    const int cur = kt & 1;
    // issue next tile's stage FIRST (overlaps with the MFMA phase below)
    if (kt + 1 < G2_NT) {
      const int k0 = (kt + 1) * G2_BK;
      const int nxt = cur ^ 1;
#pragma unroll
      for (int it = 0; it < 2; ++it) {
        int c = wid + it * 8;
        int r = c * 8 + l8;
        int src = (l7 ^ (r & 7)) << 3;
        gload_lds16(&wt[(size_t)(bm0 + r) * MPAD + k0 + src], &At[nxt][c * 512]);
        gload_lds16(&wn[(size_t)(bm0 + r) * MPAD + k0 + src], &An[nxt][c * 512]);
        gload_lds16(&mt[(size_t)(bn0 + r) * MPAD + k0 + src], &Bs[nxt][c * 512]);
      }
    }
    // compute current tile (ds_read waits lgkmcnt only; stage stays in flight)
#pragma unroll
    for (int s = 0; s < 2; ++s) {
      bf16x8 at[4], an[4], bb[2];
#pragma unroll
      for (int i = 0; i < 4; ++i) {
        int r = wr * 64 + i * 16 + r16;
        int p = (s * 4 + klane) ^ (r & 7);
        at[i] = *reinterpret_cast<const bf16x8*>(&At[cur][r * 64 + p * 8]);
        an[i] = *reinterpret_cast<const bf16x8*>(&An[cur][r * 64 + p * 8]);
      }
#pragma unroll
      for (int j = 0; j < 2; ++j) {
        int r = wc * 32 + j * 16 + r16;
        int p = (s * 4 + klane) ^ (r & 7);
        bb[j] = *reinterpret_cast<const bf16x8*>(&Bs[cur][r * 64 + p * 8]);
      }
#pragma unroll
      for (int i = 0; i < 4; ++i)
#pragma unroll
        for (int j = 0; j < 2; ++j) {
          acct[i][j] = __builtin_amdgcn_mfma_f32_16x16x32_bf16(at[i], bb[j], acct[i][j], 0, 0, 0);
          accn[i][j] = __builtin_amdgcn_mfma_f32_16x16x32_bf16(an[i], bb[j], accn[i][j], 0, 0, 0);
        }
    }
    // single barrier per K-step: drains this wave's stage loads (vmcnt) and
    // guarantees nobody still reads buf[cur] before it is overwritten
    __syncthreads();
  }

  float* outn = out + (size_t)BATCH * FDIM;
  const int rgrp = lane >> 4;
#pragma unroll
  for (int i = 0; i < 4; ++i)
#pragma unroll
    for (int j = 0; j < 2; ++j)
#pragma unroll
      for (int rg = 0; rg < 4; ++rg) {
        size_t off = (size_t)(bm0 + wr * 64 + i * 16 + rgrp * 4 + rg) * FDIM
                   + bn0 + wc * 32 + j * 16 + r16;
        out[off]  = acct[i][j][rg];
        outn[off] = accn[i][j][rg];
      }
}

// ---- entropy final reduce ----
__global__ __launch_bounds__(256) void entreduce_kernel(const float* __restrict__ ent,
                                                        float* __restrict__ out) {
  const int tid = threadIdx.x;
  float v = ent[tid];
  float u = ent[BATCH + tid];
  v = waveReduceSum(v); u = waveReduceSum(u);
  __shared__ float r1[4], r2[4];
  if ((tid & 63) == 0) { r1[tid >> 6] = v; r2[tid >> 6] = u; }
  __syncthreads();
  if (tid == 0) {
    out[(size_t)2 * BATCH * FDIM]     = ENTC * (r1[0] + r1[1] + r1[2] + r1[3]);
    out[(size_t)2 * BATCH * FDIM + 1] = ENTC * (r2[0] + r2[1] + r2[2] + r2[3]);
  }
}

// ======================= OLD fp32 FALLBACK PATH =======================
#define NM_OFF    0
#define NZ_OFF    2048
#define LOGIT_OFF 4096
#define WT_OFF    (LOGIT_OFF + 512000)
#define WNT_OFF   (WT_OFF + 512000)
#define ENT_OFF   (WNT_OFF + 512000)

__global__ __launch_bounds__(256) void rownorm_kernel(const float* __restrict__ x,
                                                      float* __restrict__ out, int cols) {
  const int r = blockIdx.x;
  const float4* xr = reinterpret_cast<const float4*>(x) + (size_t)r * (cols >> 2);
  const int n4 = cols >> 2;
  float s = 0.f;
  for (int i = threadIdx.x; i < n4; i += 256) {
    float4 v = xr[i];
    s = fmaf(v.x, v.x, s); s = fmaf(v.y, v.y, s);
    s = fmaf(v.z, v.z, s); s = fmaf(v.w, v.w, s);
  }
  s = waveReduceSum(s);
  __shared__ float red[4];
  if ((threadIdx.x & 63) == 0) red[threadIdx.x >> 6] = s;
  __syncthreads();
  if (threadIdx.x == 0) out[r] = sqrtf(red[0] + red[1] + red[2] + red[3]);
}

#define O1_BM 64
#define O1_BN 32
#define O1_BK 64
__global__ __launch_bounds__(256) void gemm1_kernel(const float* __restrict__ z,
                                                    const float* __restrict__ mem,
                                                    const float* __restrict__ nzv,
                                                    const float* __restrict__ nmv,
                                                    float* __restrict__ logit) {
  __shared__ float As[O1_BK][O1_BM];
  __shared__ float Bs[O1_BK][O1_BN];
  const int tid = threadIdx.x;
  const int bm0 = blockIdx.y * O1_BM;
  const int bn0 = blockIdx.x * O1_BN;
  const int tm = tid >> 4, tn = tid & 15;
  float acc[4][2] = {};
  for (int k0 = 0; k0 < FDIM; k0 += O1_BK) {
#pragma unroll
    for (int it = 0; it < 4; ++it) {
      int i = tid + it * 256;
      int row = i >> 4, c4 = i & 15;
      float4 v = *reinterpret_cast<const float4*>(&z[(size_t)(bm0 + row) * FDIM + k0 + c4 * 4]);
      As[c4 * 4 + 0][row] = v.x; As[c4 * 4 + 1][row] = v.y;
      As[c4 * 4 + 2][row] = v.z; As[c4 * 4 + 3][row] = v.w;
    }
#pragma unroll
    for (int it = 0; it < 2; ++it) {
      int i = tid + it * 256;
      int row = i >> 4, c4 = i & 15;
      int gm = bn0 + row;
      float4 v = make_float4(0.f, 0.f, 0.f, 0.f);
      if (gm < MSLOTS)
        v = *reinterpret_cast<const float4*>(&mem[(size_t)gm * FDIM + k0 + c4 * 4]);
      Bs[c4 * 4 + 0][row] = v.x; Bs[c4 * 4 + 1][row] = v.y;
      Bs[c4 * 4 + 2][row] = v.z; Bs[c4 * 4 + 3][row] = v.w;
    }
    __syncthreads();
#pragma unroll
    for (int kk = 0; kk < O1_BK; ++kk) {
      const float* ap = &As[kk][tm * 4];
      const float* bp = &Bs[kk][tn * 2];
      float a0 = ap[0], a1 = ap[1], a2 = ap[2], a3 = ap[3];
      float b0 = bp[0], b1 = bp[1];
      acc[0][0] = fmaf(a0, b0, acc[0][0]); acc[0][1] = fmaf(a0, b1, acc[0][1]);
      acc[1][0] = fmaf(a1, b0, acc[1][0]); acc[1][1] = fmaf(a1, b1, acc[1][1]);
      acc[2][0] = fmaf(a2, b0, acc[2][0]); acc[2][1] = fmaf(a2, b1, acc[2][1]);
      acc[3][0] = fmaf(a3, b0, acc[3][0]); acc[3][1] = fmaf(a3, b1, acc[3][1]);
    }
    __syncthreads();
  }
  float nzr[4];
#pragma unroll
  for (int i = 0; i < 4; ++i) nzr[i] = nzv[bm0 + tm * 4 + i];
#pragma unroll
  for (int j = 0; j < 2; ++j) {
    int col = bn0 + tn * 2 + j;
    if (col < MSLOTS) {
      float nmr = nmv[col];
#pragma unroll
      for (int i = 0; i < 4; ++i)
        logit[(size_t)(bm0 + tm * 4 + i) * MSLOTS + col] = acc[i][j] / fmaxf(nzr[i] * nmr, CEPS);
    }
  }
}

__global__ __launch_bounds__(256) void softmax_kernel(const float* __restrict__ logit,
                                                      const int* __restrict__ labels,
                                                      float* __restrict__ wt,
                                                      float* __restrict__ wnt,
                                                      float* __restrict__ ent) {
  const int b = blockIdx.x;
  const int tid = threadIdx.x;
  __shared__ float sh[MSLOTS];
  __shared__ float red[4], red2[4];
  const float* lrow = logit + (size_t)b * MSLOTS;
  float mx = -3.4e38f;
  for (int m = tid; m < MSLOTS; m += 256) {
    float v = lrow[m]; sh[m] = v; mx = fmaxf(mx, v);
  }
  mx = waveReduceMax(mx);
  if ((tid & 63) == 0) red[tid >> 6] = mx;
  __syncthreads();
  mx = fmaxf(fmaxf(red[0], red[1]), fmaxf(red[2], red[3]));
  __syncthreads();
  float s = 0.f;
  for (int m = tid; m < MSLOTS; m += 256) {
    float e = expf(sh[m] - mx); sh[m] = e; s += e;
  }
  s = waveReduceSum(s);
  if ((tid & 63) == 0) red[tid >> 6] = s;
  __syncthreads();
  s = red[0] + red[1] + red[2] + red[3];
  __syncthreads();
  const float inv = 1.f / s;
  const int c = labels[b];
  const int t0 = c * MPC, t1 = t0 + MPC;
  float st = 0.f, sn = 0.f;
  for (int m = tid; m < MSLOTS; m += 256) {
    float w = sh[m] * inv;
    float k = (w > THRESH) ? w : 0.f;
    sh[m] = k;
    bool tgt = (m >= t0) && (m < t1);
    st += tgt ? k : 0.f;
    sn += tgt ? 0.f : k;
  }
  st = waveReduceSum(st); sn = waveReduceSum(sn);
  if ((tid & 63) == 0) { red[tid >> 6] = st; red2[tid >> 6] = sn; }
  __syncthreads();
  st = red[0] + red[1] + red[2] + red[3];
  sn = red2[0] + red2[1] + red2[2] + red2[3];
  __syncthreads();
  const float rt = 1.f / st, rn = 1.f / sn;
  float et = 0.f, en = 0.f;
  float* wtr = wt + (size_t)b * MSLOTS;
  float* wnr = wnt + (size_t)b * MSLOTS;
  for (int m = tid; m < MSLOTS; m += 256) {
    float k = sh[m];
    bool tgt = (m >= t0) && (m < t1);
    float a  = tgt ? k * rt : 0.f;
    float cn = tgt ? 0.f : k * rn;
    wtr[m] = a;
    wnr[m] = cn;
    et -= a  * logf(a  + LEPS);
    en -= cn * logf(cn + LEPS);
  }
  et = waveReduceSum(et); en = waveReduceSum(en);
  if ((tid & 63) == 0) { red[tid >> 6] = et; red2[tid >> 6] = en; }
  __syncthreads();
  if (tid == 0) {
    ent[b]         = red[0] + red[1] + red[2] + red[3];
    ent[BATCH + b] = red2[0] + red2[1] + red2[2] + red2[3];
  }
}

#define O2_BM 64
#define O2_BN 64
#define O2_BK 32
__global__ __launch_bounds__(256) void gemm23_kernel(const float* __restrict__ wt,
                                                     const float* __restrict__ wnt,
                                                     const float* __restrict__ mem,
                                                     float* __restrict__ out) {
  __shared__ float Wts[O2_BK][O2_BM];
  __shared__ float Wns[O2_BK][O2_BM];
  __shared__ float Ms[O2_BK][O2_BN];
  const int tid = threadIdx.x;
  const int bm0 = blockIdx.y * O2_BM;
  const int bn0 = blockIdx.x * O2_BN;
  const int tm = tid >> 4, tn = tid & 15;
  float at[4][4] = {}, an[4][4] = {};
  for (int k0 = 0; k0 < MSLOTS; k0 += O2_BK) {
#pragma unroll
    for (int it = 0; it < 2; ++it) {
      int i = tid + it * 256;
      int row = i >> 3, c4 = i & 7;
      int gk = k0 + c4 * 4;
      float4 vt = make_float4(0.f, 0.f, 0.f, 0.f), vn = vt;
      if (gk < MSLOTS) {
        vt = *reinterpret_cast<const float4*>(&wt [(size_t)(bm0 + row) * MSLOTS + gk]);
        vn = *reinterpret_cast<const float4*>(&wnt[(size_t)(bm0 + row) * MSLOTS + gk]);
      }
      Wts[c4 * 4 + 0][row] = vt.x; Wts[c4 * 4 + 1][row] = vt.y;
      Wts[c4 * 4 + 2][row] = vt.z; Wts[c4 * 4 + 3][row] = vt.w;
      Wns[c4 * 4 + 0][row] = vn.x; Wns[c4 * 4 + 1][row] = vn.y;
      Wns[c4 * 4 + 2][row] = vn.z; Wns[c4 * 4 + 3][row] = vn.w;
    }
#pragma unroll
    for (int it = 0; it < 2; ++it) {
      int i = tid + it * 256;
      int row = i >> 4, c4 = i & 15;
      int gk = k0 + row;
      float4 v = make_float4(0.f, 0.f, 0.f, 0.f);
      if (gk < MSLOTS)
        v = *reinterpret_cast<const float4*>(&mem[(size_t)gk * FDIM + bn0 + c4 * 4]);
      *reinterpret_cast<float4*>(&Ms[row][c4 * 4]) = v;
    }
    __syncthreads();
#pragma unroll
    for (int kk = 0; kk < O2_BK; ++kk) {
      const float* tp = &Wts[kk][tm * 4];
      const float* np = &Wns[kk][tm * 4];
      const float* bp = &Ms[kk][tn * 4];
      float b0 = bp[0], b1 = bp[1], b2 = bp[2], b3 = bp[3];
#pragma unroll
      for (int i = 0; i < 4; ++i) {
        float a = tp[i], cn = np[i];
        at[i][0] = fmaf(a,  b0, at[i][0]); at[i][1] = fmaf(a,  b1, at[i][1]);
        at[i][2] = fmaf(a,  b2, at[i][2]); at[i][3] = fmaf(a,  b3, at[i][3]);
        an[i][0] = fmaf(cn, b0, an[i][0]); an[i][1] = fmaf(cn, b1, an[i][1]);
        an[i][2] = fmaf(cn, b2, an[i][2]); an[i][3] = fmaf(cn, b3, an[i][3]);
      }
    }
    __syncthreads();
  }
  float* outt = out;
  float* outn = out + (size_t)BATCH * FDIM;
#pragma unroll
  for (int i = 0; i < 4; ++i) {
    size_t off = (size_t)(bm0 + tm * 4 + i) * FDIM + bn0 + tn * 4;
    *reinterpret_cast<float4*>(&outt[off]) = make_float4(at[i][0], at[i][1], at[i][2], at[i][3]);
    *reinterpret_cast<float4*>(&outn[off]) = make_float4(an[i][0], an[i][1], an[i][2], an[i][3]);
  }
}

// ======================= host =======================
extern "C" void kernel_launch(void* const* d_in, const int* in_sizes, int n_in,
                              void* d_out, int out_size, void* d_ws, size_t ws_size,
                              hipStream_t stream) {
  const float* z      = (const float*)d_in[0];
  const int*   labels = (const int*)d_in[1];
  const float* mem    = (const float*)d_in[2];
  float* out = (float*)d_out;
  char*  wsb = (char*)d_ws;

  // new-path workspace layout (bytes)
  constexpr size_t NM_B   = 0;
  constexpr size_t NZ_B   = 8192;
  constexpr size_t ZB_B   = 16384;
  constexpr size_t MB_B   = ZB_B + (size_t)BATCH * FDIM * 2;
  constexpr size_t MT_B   = MB_B + (size_t)MPAD * FDIM * 2;
  constexpr size_t WTB_B  = MT_B + (size_t)FDIM * MPAD * 2;
  constexpr size_t WNB_B  = WTB_B + (size_t)BATCH * MPAD * 2;
  constexpr size_t NP_B   = WNB_B + (size_t)BATCH * MPAD * 2;
  constexpr size_t PART_B = NP_B + (size_t)(MPAD + BATCH) * NFB * 4;
  constexpr size_t ENT_B  = PART_B + (size_t)SPLITK * BATCH * MPAD * 4;
  constexpr size_t NEED   = ENT_B + 2048;

  if (ws_size >= NEED) {
    float* nm = (float*)(wsb + NM_B);
    float* nz = (float*)(wsb + NZ_B);
    unsigned short* zb = (unsigned short*)(wsb + ZB_B);
    unsigned short* mb = (unsigned short*)(wsb + MB_B);
    unsigned short* mt = (unsigned short*)(wsb + MT_B);
    unsigned short* wt = (unsigned short*)(wsb + WTB_B);
    unsigned short* wn = (unsigned short*)(wsb + WNB_B);
    float* npart = (float*)(wsb + NP_B);
    float* part  = (float*)(wsb + PART_B);
    float* ent   = (float*)(wsb + ENT_B);

    convert_all_kernel<<<dim3(NFB, (MPAD + BATCH) / 64), 256, 0, stream>>>(
        z, mem, zb, mb, mt, npart);
    normfin_kernel<<<MPAD + BATCH, 64, 0, stream>>>(npart, nm, nz);
    gemm1_mfma<<<dim3(MPAD / G1_BN, BATCH / G1_BM, SPLITK), 256, 0, stream>>>(zb, mb, part);
    softmax2_kernel<<<BATCH, 256, 0, stream>>>(part, nz, nm, labels, wt, wn, ent);
    gemm23_mfma<<<dim3(FDIM / G2_BN, BATCH / G2_BM), 512, 0, stream>>>(wt, wn, mt, out);
    entreduce_kernel<<<1, 256, 0, stream>>>(ent, out);
  } else {
    float* ws    = (float*)d_ws;
    float* nm    = ws + NM_OFF;
    float* nzv   = ws + NZ_OFF;
    float* logit = ws + LOGIT_OFF;
    float* wt    = ws + WT_OFF;
    float* wnt   = ws + WNT_OFF;
    float* ent   = ws + ENT_OFF;

    rownorm_kernel<<<MSLOTS, 256, 0, stream>>>(mem, nm, FDIM);
    rownorm_kernel<<<BATCH, 256, 0, stream>>>(z, nzv, FDIM);
    gemm1_kernel<<<dim3((MSLOTS + O1_BN - 1) / O1_BN, BATCH / O1_BM), 256, 0, stream>>>(
        z, mem, nzv, nm, logit);
    softmax_kernel<<<BATCH, 256, 0, stream>>>(logit, labels, wt, wnt, ent);
    gemm23_kernel<<<dim3(FDIM / O2_BN, BATCH / O2_BM), 256, 0, stream>>>(wt, wnt, mem, out);
    entreduce_kernel<<<1, 256, 0, stream>>>(ent, out);
  }
}

// Round 10
// 146.554 us; speedup vs baseline: 1.0654x; 1.0463x over previous
//
#include <hip/hip_runtime.h>
#include <math.h>

#define BATCH 256
#define FDIM 16384
#define MSLOTS 2000
#define MPAD 2048
#define NCLS 10
#define MPC 200    // memories per class
#define NFB2 128   // npart partials per row (f-tiles of 128)

static constexpr float THRESH = 2e-4f;
static constexpr float ENTC   = 2e-4f;
static constexpr float CEPS   = 1e-8f;
static constexpr float LEPS   = 1e-12f;

using bf16x8 = __attribute__((ext_vector_type(8))) short;
using f32x4  = __attribute__((ext_vector_type(4))) float;
using us8    = __attribute__((ext_vector_type(8))) unsigned short;

__device__ __forceinline__ unsigned short f2bf(float f) {
  unsigned u = __float_as_uint(f);
  unsigned r = u + 0x7fffu + ((u >> 16) & 1u);
  return (unsigned short)(r >> 16);
}

__device__ __forceinline__ void gload_lds16(const unsigned short* g, unsigned short* l) {
  __builtin_amdgcn_global_load_lds(
      (const __attribute__((address_space(1))) void*)g,
      (__attribute__((address_space(3))) void*)l, 16, 0, 0);
}
__device__ __forceinline__ void gload_lds16f(const float* g, float* l) {
  __builtin_amdgcn_global_load_lds(
      (const __attribute__((address_space(1))) void*)g,
      (__attribute__((address_space(3))) void*)l, 16, 0, 0);
}

__device__ __forceinline__ float waveReduceSum(float v) {
#pragma unroll
  for (int o = 32; o > 0; o >>= 1) v += __shfl_xor(v, o);
  return v;
}
__device__ __forceinline__ float waveReduceMax(float v) {
#pragma unroll
  for (int o = 32; o > 0; o >>= 1) v = fmaxf(v, __shfl_xor(v, o));
  return v;
}

// ======================= bf16 MFMA PATH =======================

// ---- convert via global_load_lds deep pipeline ----
// Each block: stage 64 rows x 128 f of fp32 into LINEAR LDS via 32x 1KB
// global_load_lds chunks (8 per wave, back-to-back, zero data VGPRs), then
// convert out of LDS: row-major bf16 + packed-swizzled transpose + reg norms.
// grid: x = FDIM/128 = 128 f-tiles, y = 36 row-tiles (0..31 mem, 32..35 z)
__global__ __launch_bounds__(256) void convert_all_kernel(
    const float* __restrict__ z, const float* __restrict__ mem,
    unsigned short* __restrict__ zb, unsigned short* __restrict__ mb,
    unsigned short* __restrict__ mt, float* __restrict__ npart) {
  __shared__ float F[64 * 128];          // 32 KB fp32 tile (linear: gload_lds dest)
  __shared__ unsigned int P[64 * 66];    // 16.9 KB packed transpose staging
  __shared__ float rsum[64 * 33];        // 8.4 KB norm partials
  const int tid = threadIdx.x;
  const int lane = tid & 63, wid = tid >> 6;
  const int f0 = blockIdx.x * 128;
  const int yt = blockIdx.y;
  const bool isMem = (yt < MPAD / 64);
  const int r0 = isMem ? yt * 64 : (yt - MPAD / 64) * 64;
  const float* src = isMem ? mem : z;
  unsigned short* dst = isMem ? mb : zb;

  // stage: chunk c covers rows 2c, 2c+1 (512B each); lane -> row 2c+(l>>5),
  // cols (l&31)*4 .. +3. 8 chunks per wave issued with no dependent waits.
#pragma unroll
  for (int it = 0; it < 8; ++it) {
    const int c = wid * 8 + it;
    int gr = r0 + 2 * c + (lane >> 5);
    if (isMem && gr >= MSLOTS) gr = MSLOTS - 1;   // safe clamp; zeroed below
    gload_lds16f(&src[(size_t)gr * FDIM + f0 + (lane & 31) * 4], &F[c * 256]);
  }
  __syncthreads();

  // convert + row-major bf16 write + P staging + norm partials
  const int q = tid & 31;        // f-quad (4 floats)
  const int mb8 = tid >> 5;      // base row 0..7
  const int fq = f0 + q * 4;
#pragma unroll
  for (int it = 0; it < 8; ++it) {
    const int m = mb8 + it * 8;
    const int gr = r0 + m;
    const bool valid = !isMem || gr < MSLOTS;
    float4 v = make_float4(0.f, 0.f, 0.f, 0.f);
    if (valid) v = *reinterpret_cast<const float4*>(&F[m * 128 + q * 4]);
    rsum[m * 33 + q] = fmaf(v.x, v.x, fmaf(v.y, v.y, fmaf(v.z, v.z, v.w * v.w)));
    unsigned lo = ((unsigned)f2bf(v.y) << 16) | f2bf(v.x);
    unsigned hi = ((unsigned)f2bf(v.w) << 16) | f2bf(v.z);
    *reinterpret_cast<uint2*>(&dst[(size_t)gr * FDIM + fq]) = make_uint2(lo, hi);
    if (isMem) {
      const int x = (m >> 1) & 15;
      *reinterpret_cast<uint2*>(&P[m * 66 + 2 * (q ^ x)]) = make_uint2(lo, hi);
    }
  }
  __syncthreads();

  // packed transpose out of LDS -> mt[f][m] (mem only)
  if (isMem) {
    const int h = tid & 7;         // m-octet 0..7
    const int j0 = tid >> 3;       // f-pair base 0..31
#pragma unroll
    for (int half = 0; half < 2; ++half) {
      const int j = j0 + half * 32;      // f-pair 0..63
      unsigned p[8];
#pragma unroll
      for (int s = 0; s < 8; ++s) {
        const int m = h * 8 + s;
        const int col = j ^ (((m >> 1) & 15) << 1);
        p[s] = P[m * 66 + col];
      }
      unsigned lo[4], hi[4];
#pragma unroll
      for (int t = 0; t < 4; ++t) {
        const unsigned p0 = p[2 * t], p1 = p[2 * t + 1];
        lo[t] = (p1 << 16) | (p0 & 0xFFFFu);          // f = 2j
        hi[t] = (p1 & 0xFFFF0000u) | (p0 >> 16);      // f = 2j+1
      }
      const size_t base = (size_t)(f0 + 2 * j) * MPAD + r0 + h * 8;
      *reinterpret_cast<uint4*>(&mt[base])        = make_uint4(lo[0], lo[1], lo[2], lo[3]);
      *reinterpret_cast<uint4*>(&mt[base + MPAD]) = make_uint4(hi[0], hi[1], hi[2], hi[3]);
    }
  }
  // norm partial reduce: 64 threads, one row each
  if (tid < 64) {
    float s = 0.f;
#pragma unroll
    for (int c = 0; c < 32; ++c) s += rsum[tid * 33 + c];
    const int row = isMem ? (r0 + tid) : (MPAD + r0 + tid);
    npart[(size_t)row * NFB2 + blockIdx.x] = s;
  }
}

// ---- finalize norms: nm[0..2047], nz[0..255] ----
__global__ __launch_bounds__(64) void normfin_kernel(const float* __restrict__ npart,
                                                     float* __restrict__ nm,
                                                     float* __restrict__ nz) {
  const int row = blockIdx.x;
  const int lane = threadIdx.x;
  const float* p = npart + (size_t)row * NFB2;
  float s = p[lane] + p[lane + 64];
  s = waveReduceSum(s);
  if (lane == 0) {
    float v = sqrtf(s);
    if (row < MPAD) nm[row] = v;
    else            nz[row - MPAD] = v;
  }
}

// ---- GEMM1 (MFMA): partial[s][b][m] = sum_k z_bf16[b][k] * mem_bf16[m][k] ----
#define G1_BM 128
#define G1_BN 64
#define G1_BK 64
#define SPLITK 8
#define KCHUNK (FDIM / SPLITK)   // 2048

__global__ __launch_bounds__(256, 2) void gemm1_mfma(const unsigned short* __restrict__ zb,
                                                     const unsigned short* __restrict__ mb,
                                                     float* __restrict__ part) {
  __shared__ unsigned short As[G1_BM * G1_BK];  // rows of 64 bf16 (128 B), slot-swizzled
  __shared__ unsigned short Bs[G1_BN * G1_BK];
  const int tid = threadIdx.x;
  const int lane = tid & 63, wid = tid >> 6;
  const int bn0 = blockIdx.x * G1_BN;
  const int bm0 = blockIdx.y * G1_BM;
  const int kbase = blockIdx.z * KCHUNK;
  const int wr = wid >> 1, wc = wid & 1;  // wave tile 64x32
  const int l8 = lane >> 3, l7 = lane & 7;
  const int r16 = lane & 15, klane = lane >> 4;

  f32x4 acc[4][2] = {};

  for (int kt = 0; kt < KCHUNK; kt += G1_BK) {
    const int kg = kbase + kt;
#pragma unroll
    for (int it = 0; it < 4; ++it) {
      int c = wid + it * 4;
      int r = c * 8 + l8;
      int src = (l7 ^ (r & 7)) << 3;
      gload_lds16(&zb[(size_t)(bm0 + r) * FDIM + kg + src], &As[c * 512]);
    }
#pragma unroll
    for (int it = 0; it < 2; ++it) {
      int c = wid + it * 4;
      int r = c * 8 + l8;
      int src = (l7 ^ (r & 7)) << 3;
      gload_lds16(&mb[(size_t)(bn0 + r) * FDIM + kg + src], &Bs[c * 512]);
    }
    __syncthreads();
#pragma unroll
    for (int s = 0; s < 2; ++s) {
      bf16x8 a[4], bb[2];
#pragma unroll
      for (int i = 0; i < 4; ++i) {
        int r = wr * 64 + i * 16 + r16;
        int p = (s * 4 + klane) ^ (r & 7);
        a[i] = *reinterpret_cast<const bf16x8*>(&As[r * 64 + p * 8]);
      }
#pragma unroll
      for (int j = 0; j < 2; ++j) {
        int r = wc * 32 + j * 16 + r16;
        int p = (s * 4 + klane) ^ (r & 7);
        bb[j] = *reinterpret_cast<const bf16x8*>(&Bs[r * 64 + p * 8]);
      }
#pragma unroll
      for (int i = 0; i < 4; ++i)
#pragma unroll
        for (int j = 0; j < 2; ++j)
          acc[i][j] = __builtin_amdgcn_mfma_f32_16x16x32_bf16(a[i], bb[j], acc[i][j], 0, 0, 0);
    }
    __syncthreads();
  }
  const int rgrp = lane >> 4;
  float* pbase = part + (size_t)blockIdx.z * BATCH * MPAD;
#pragma unroll
  for (int i = 0; i < 4; ++i)
#pragma unroll
    for (int j = 0; j < 2; ++j)
#pragma unroll
      for (int rg = 0; rg < 4; ++rg) {
        int row = bm0 + wr * 64 + i * 16 + rgrp * 4 + rg;
        int col = bn0 + wc * 32 + j * 16 + r16;
        pbase[(size_t)row * MPAD + col] = acc[i][j][rg];
      }
}

// ---- softmax: fuse split-K reduce + norm divide; write bf16 w_t / w_nt; entropy fp32 ----
__global__ __launch_bounds__(256) void softmax2_kernel(const float* __restrict__ part,
                                                       const float* __restrict__ nzv,
                                                       const float* __restrict__ nmv,
                                                       const int* __restrict__ labels,
                                                       unsigned short* __restrict__ wt,
                                                       unsigned short* __restrict__ wn,
                                                       float* __restrict__ ent) {
  const int b = blockIdx.x, tid = threadIdx.x;
  __shared__ float sh[MSLOTS];
  __shared__ float red[4], red2[4];
  const float nzb = nzv[b];
  float mx = -3.4e38f;
  for (int m = tid; m < MSLOTS; m += 256) {
    float s = 0.f;
#pragma unroll
    for (int sp = 0; sp < SPLITK; ++sp)
      s += part[((size_t)sp * BATCH + b) * MPAD + m];
    float v = s / fmaxf(nzb * nmv[m], CEPS);
    sh[m] = v; mx = fmaxf(mx, v);
  }
  mx = waveReduceMax(mx);
  if ((tid & 63) == 0) red[tid >> 6] = mx;
  __syncthreads();
  mx = fmaxf(fmaxf(red[0], red[1]), fmaxf(red[2], red[3]));
  __syncthreads();

  float s = 0.f;
  for (int m = tid; m < MSLOTS; m += 256) {
    float e = expf(sh[m] - mx); sh[m] = e; s += e;
  }
  s = waveReduceSum(s);
  if ((tid & 63) == 0) red[tid >> 6] = s;
  __syncthreads();
  s = red[0] + red[1] + red[2] + red[3];
  __syncthreads();

  const float inv = 1.f / s;
  const int c = labels[b];
  const int t0 = c * MPC, t1 = t0 + MPC;
  float st = 0.f, sn = 0.f;
  for (int m = tid; m < MSLOTS; m += 256) {
    float w = sh[m] * inv;
    float k = (w > THRESH) ? w : 0.f;
    sh[m] = k;
    bool tgt = (m >= t0) && (m < t1);
    st += tgt ? k : 0.f;
    sn += tgt ? 0.f : k;
  }
  st = waveReduceSum(st); sn = waveReduceSum(sn);
  if ((tid & 63) == 0) { red[tid >> 6] = st; red2[tid >> 6] = sn; }
  __syncthreads();
  st = red[0] + red[1] + red[2] + red[3];
  sn = red2[0] + red2[1] + red2[2] + red2[3];
  __syncthreads();

  const float rt = 1.f / st, rn = 1.f / sn;
  float et = 0.f, en = 0.f;
  unsigned short* wtr = wt + (size_t)b * MPAD;
  unsigned short* wnr = wn + (size_t)b * MPAD;
  for (int m = tid; m < MPAD; m += 256) {
    float a = 0.f, cn = 0.f;
    if (m < MSLOTS) {
      float k = sh[m];
      bool tgt = (m >= t0) && (m < t1);
      a  = tgt ? k * rt : 0.f;
      cn = tgt ? 0.f : k * rn;
      et -= a  * logf(a  + LEPS);
      en -= cn * logf(cn + LEPS);
    }
    wtr[m] = f2bf(a);
    wnr[m] = f2bf(cn);
  }
  et = waveReduceSum(et); en = waveReduceSum(en);
  if ((tid & 63) == 0) { red[tid >> 6] = et; red2[tid >> 6] = en; }
  __syncthreads();
  if (tid == 0) {
    ent[b]         = red[0] + red[1] + red[2] + red[3];
    ent[BATCH + b] = red2[0] + red2[1] + red2[2] + red2[3];
  }
}

// ---- GEMM2+3 (MFMA, fused dual accumulator, single-buffer r8 version) ----
#define G2_BM 128
#define G2_BN 128
#define G2_BK 64

__global__ __launch_bounds__(512, 2) void gemm23_mfma(const unsigned short* __restrict__ wt,
                                                      const unsigned short* __restrict__ wn,
                                                      const unsigned short* __restrict__ mt,
                                                      float* __restrict__ out) {
  __shared__ unsigned short At[G2_BM * G2_BK];
  __shared__ unsigned short An[G2_BM * G2_BK];
  __shared__ unsigned short Bs[G2_BN * G2_BK];
  const int tid = threadIdx.x, lane = tid & 63, wid = tid >> 6;
  const int bn0 = blockIdx.x * G2_BN;  // f
  const int bm0 = blockIdx.y * G2_BM;  // batch
  const int wr = wid >> 2, wc = wid & 3;  // 2x4 waves, each 64x32
  const int l8 = lane >> 3, l7 = lane & 7;
  const int r16 = lane & 15, klane = lane >> 4;

  f32x4 acct[4][2] = {}, accn[4][2] = {};

  for (int k0 = 0; k0 < MPAD; k0 += G2_BK) {
#pragma unroll
    for (int it = 0; it < 2; ++it) {
      int c = wid + it * 8;  // 16 chunks over 8 waves
      int r = c * 8 + l8;
      int src = (l7 ^ (r & 7)) << 3;
      gload_lds16(&wt[(size_t)(bm0 + r) * MPAD + k0 + src], &At[c * 512]);
      gload_lds16(&wn[(size_t)(bm0 + r) * MPAD + k0 + src], &An[c * 512]);
      gload_lds16(&mt[(size_t)(bn0 + r) * MPAD + k0 + src], &Bs[c * 512]);
    }
    __syncthreads();
#pragma unroll
    for (int s = 0; s < 2; ++s) {
      bf16x8 at[4], an[4], bb[2];
#pragma unroll
      for (int i = 0; i < 4; ++i) {
        int r = wr * 64 + i * 16 + r16;
        int p = (s * 4 + klane) ^ (r & 7);
        at[i] = *reinterpret_cast<const bf16x8*>(&At[r * 64 + p * 8]);
        an[i] = *reinterpret_cast<const bf16x8*>(&An[r * 64 + p * 8]);
      }
#pragma unroll
      for (int j = 0; j < 2; ++j) {
        int r = wc * 32 + j * 16 + r16;
        int p = (s * 4 + klane) ^ (r & 7);
        bb[j] = *reinterpret_cast<const bf16x8*>(&Bs[r * 64 + p * 8]);
      }
#pragma unroll
      for (int i = 0; i < 4; ++i)
#pragma unroll
        for (int j = 0; j < 2; ++j) {
          acct[i][j] = __builtin_amdgcn_mfma_f32_16x16x32_bf16(at[i], bb[j], acct[i][j], 0, 0, 0);
          accn[i][j] = __builtin_amdgcn_mfma_f32_16x16x32_bf16(an[i], bb[j], accn[i][j], 0, 0, 0);
        }
    }
    __syncthreads();
  }
  float* outn = out + (size_t)BATCH * FDIM;
  const int rgrp = lane >> 4;
#pragma unroll
  for (int i = 0; i < 4; ++i)
#pragma unroll
    for (int j = 0; j < 2; ++j)
#pragma unroll
      for (int rg = 0; rg < 4; ++rg) {
        size_t off = (size_t)(bm0 + wr * 64 + i * 16 + rgrp * 4 + rg) * FDIM
                   + bn0 + wc * 32 + j * 16 + r16;
        out[off]  = acct[i][j][rg];
        outn[off] = accn[i][j][rg];
      }
}

// ---- entropy final reduce ----
__global__ __launch_bounds__(256) void entreduce_kernel(const float* __restrict__ ent,
                                                        float* __restrict__ out) {
  const int tid = threadIdx.x;
  float v = ent[tid];
  float u = ent[BATCH + tid];
  v = waveReduceSum(v); u = waveReduceSum(u);
  __shared__ float r1[4], r2[4];
  if ((tid & 63) == 0) { r1[tid >> 6] = v; r2[tid >> 6] = u; }
  __syncthreads();
  if (tid == 0) {
    out[(size_t)2 * BATCH * FDIM]     = ENTC * (r1[0] + r1[1] + r1[2] + r1[3]);
    out[(size_t)2 * BATCH * FDIM + 1] = ENTC * (r2[0] + r2[1] + r2[2] + r2[3]);
  }
}

// ======================= OLD fp32 FALLBACK PATH =======================
#define NM_OFF    0
#define NZ_OFF    2048
#define LOGIT_OFF 4096
#define WT_OFF    (LOGIT_OFF + 512000)
#define WNT_OFF   (WT_OFF + 512000)
#define ENT_OFF   (WNT_OFF + 512000)

__global__ __launch_bounds__(256) void rownorm_kernel(const float* __restrict__ x,
                                                      float* __restrict__ out, int cols) {
  const int r = blockIdx.x;
  const float4* xr = reinterpret_cast<const float4*>(x) + (size_t)r * (cols >> 2);
  const int n4 = cols >> 2;
  float s = 0.f;
  for (int i = threadIdx.x; i < n4; i += 256) {
    float4 v = xr[i];
    s = fmaf(v.x, v.x, s); s = fmaf(v.y, v.y, s);
    s = fmaf(v.z, v.z, s); s = fmaf(v.w, v.w, s);
  }
  s = waveReduceSum(s);
  __shared__ float red[4];
  if ((threadIdx.x & 63) == 0) red[threadIdx.x >> 6] = s;
  __syncthreads();
  if (threadIdx.x == 0) out[r] = sqrtf(red[0] + red[1] + red[2] + red[3]);
}

#define O1_BM 64
#define O1_BN 32
#define O1_BK 64
__global__ __launch_bounds__(256) void gemm1_kernel(const float* __restrict__ z,
                                                    const float* __restrict__ mem,
                                                    const float* __restrict__ nzv,
                                                    const float* __restrict__ nmv,
                                                    float* __restrict__ logit) {
  __shared__ float As[O1_BK][O1_BM];
  __shared__ float Bs[O1_BK][O1_BN];
  const int tid = threadIdx.x;
  const int bm0 = blockIdx.y * O1_BM;
  const int bn0 = blockIdx.x * O1_BN;
  const int tm = tid >> 4, tn = tid & 15;
  float acc[4][2] = {};
  for (int k0 = 0; k0 < FDIM; k0 += O1_BK) {
#pragma unroll
    for (int it = 0; it < 4; ++it) {
      int i = tid + it * 256;
      int row = i >> 4, c4 = i & 15;
      float4 v = *reinterpret_cast<const float4*>(&z[(size_t)(bm0 + row) * FDIM + k0 + c4 * 4]);
      As[c4 * 4 + 0][row] = v.x; As[c4 * 4 + 1][row] = v.y;
      As[c4 * 4 + 2][row] = v.z; As[c4 * 4 + 3][row] = v.w;
    }
#pragma unroll
    for (int it = 0; it < 2; ++it) {
      int i = tid + it * 256;
      int row = i >> 4, c4 = i & 15;
      int gm = bn0 + row;
      float4 v = make_float4(0.f, 0.f, 0.f, 0.f);
      if (gm < MSLOTS)
        v = *reinterpret_cast<const float4*>(&mem[(size_t)gm * FDIM + k0 + c4 * 4]);
      Bs[c4 * 4 + 0][row] = v.x; Bs[c4 * 4 + 1][row] = v.y;
      Bs[c4 * 4 + 2][row] = v.z; Bs[c4 * 4 + 3][row] = v.w;
    }
    __syncthreads();
#pragma unroll
    for (int kk = 0; kk < O1_BK; ++kk) {
      const float* ap = &As[kk][tm * 4];
      const float* bp = &Bs[kk][tn * 2];
      float a0 = ap[0], a1 = ap[1], a2 = ap[2], a3 = ap[3];
      float b0 = bp[0], b1 = bp[1];
      acc[0][0] = fmaf(a0, b0, acc[0][0]); acc[0][1] = fmaf(a0, b1, acc[0][1]);
      acc[1][0] = fmaf(a1, b0, acc[1][0]); acc[1][1] = fmaf(a1, b1, acc[1][1]);
      acc[2][0] = fmaf(a2, b0, acc[2][0]); acc[2][1] = fmaf(a2, b1, acc[2][1]);
      acc[3][0] = fmaf(a3, b0, acc[3][0]); acc[3][1] = fmaf(a3, b1, acc[3][1]);
    }
    __syncthreads();
  }
  float nzr[4];
#pragma unroll
  for (int i = 0; i < 4; ++i) nzr[i] = nzv[bm0 + tm * 4 + i];
#pragma unroll
  for (int j = 0; j < 2; ++j) {
    int col = bn0 + tn * 2 + j;
    if (col < MSLOTS) {
      float nmr = nmv[col];
#pragma unroll
      for (int i = 0; i < 4; ++i)
        logit[(size_t)(bm0 + tm * 4 + i) * MSLOTS + col] = acc[i][j] / fmaxf(nzr[i] * nmr, CEPS);
    }
  }
}

__global__ __launch_bounds__(256) void softmax_kernel(const float* __restrict__ logit,
                                                      const int* __restrict__ labels,
                                                      float* __restrict__ wt,
                                                      float* __restrict__ wnt,
                                                      float* __restrict__ ent) {
  const int b = blockIdx.x;
  const int tid = threadIdx.x;
  __shared__ float sh[MSLOTS];
  __shared__ float red[4], red2[4];
  const float* lrow = logit + (size_t)b * MSLOTS;
  float mx = -3.4e38f;
  for (int m = tid; m < MSLOTS; m += 256) {
    float v = lrow[m]; sh[m] = v; mx = fmaxf(mx, v);
  }
  mx = waveReduceMax(mx);
  if ((tid & 63) == 0) red[tid >> 6] = mx;
  __syncthreads();
  mx = fmaxf(fmaxf(red[0], red[1]), fmaxf(red[2], red[3]));
  __syncthreads();
  float s = 0.f;
  for (int m = tid; m < MSLOTS; m += 256) {
    float e = expf(sh[m] - mx); sh[m] = e; s += e;
  }
  s = waveReduceSum(s);
  if ((tid & 63) == 0) red[tid >> 6] = s;
  __syncthreads();
  s = red[0] + red[1] + red[2] + red[3];
  __syncthreads();
  const float inv = 1.f / s;
  const int c = labels[b];
  const int t0 = c * MPC, t1 = t0 + MPC;
  float st = 0.f, sn = 0.f;
  for (int m = tid; m < MSLOTS; m += 256) {
    float w = sh[m] * inv;
    float k = (w > THRESH) ? w : 0.f;
    sh[m] = k;
    bool tgt = (m >= t0) && (m < t1);
    st += tgt ? k : 0.f;
    sn += tgt ? 0.f : k;
  }
  st = waveReduceSum(st); sn = waveReduceSum(sn);
  if ((tid & 63) == 0) { red[tid >> 6] = st; red2[tid >> 6] = sn; }
  __syncthreads();
  st = red[0] + red[1] + red[2] + red[3];
  sn = red2[0] + red2[1] + red2[2] + red2[3];
  __syncthreads();
  const float rt = 1.f / st, rn = 1.f / sn;
  float et = 0.f, en = 0.f;
  float* wtr = wt + (size_t)b * MSLOTS;
  float* wnr = wnt + (size_t)b * MSLOTS;
  for (int m = tid; m < MSLOTS; m += 256) {
    float k = sh[m];
    bool tgt = (m >= t0) && (m < t1);
    float a  = tgt ? k * rt : 0.f;
    float cn = tgt ? 0.f : k * rn;
    wtr[m] = a;
    wnr[m] = cn;
    et -= a  * logf(a  + LEPS);
    en -= cn * logf(cn + LEPS);
  }
  et = waveReduceSum(et); en = waveReduceSum(en);
  if ((tid & 63) == 0) { red[tid >> 6] = et; red2[tid >> 6] = en; }
  __syncthreads();
  if (tid == 0) {
    ent[b]         = red[0] + red[1] + red[2] + red[3];
    ent[BATCH + b] = red2[0] + red2[1] + red2[2] + red2[3];
  }
}

#define O2_BM 64
#define O2_BN 64
#define O2_BK 32
__global__ __launch_bounds__(256) void gemm23_kernel(const float* __restrict__ wt,
                                                     const float* __restrict__ wnt,
                                                     const float* __restrict__ mem,
                                                     float* __restrict__ out) {
  __shared__ float Wts[O2_BK][O2_BM];
  __shared__ float Wns[O2_BK][O2_BM];
  __shared__ float Ms[O2_BK][O2_BN];
  const int tid = threadIdx.x;
  const int bm0 = blockIdx.y * O2_BM;
  const int bn0 = blockIdx.x * O2_BN;
  const int tm = tid >> 4, tn = tid & 15;
  float at[4][4] = {}, an[4][4] = {};
  for (int k0 = 0; k0 < MSLOTS; k0 += O2_BK) {
#pragma unroll
    for (int it = 0; it < 2; ++it) {
      int i = tid + it * 256;
      int row = i >> 3, c4 = i & 7;
      int gk = k0 + c4 * 4;
      float4 vt = make_float4(0.f, 0.f, 0.f, 0.f), vn = vt;
      if (gk < MSLOTS) {
        vt = *reinterpret_cast<const float4*>(&wt [(size_t)(bm0 + row) * MSLOTS + gk]);
        vn = *reinterpret_cast<const float4*>(&wnt[(size_t)(bm0 + row) * MSLOTS + gk]);
      }
      Wts[c4 * 4 + 0][row] = vt.x; Wts[c4 * 4 + 1][row] = vt.y;
      Wts[c4 * 4 + 2][row] = vt.z; Wts[c4 * 4 + 3][row] = vt.w;
      Wns[c4 * 4 + 0][row] = vn.x; Wns[c4 * 4 + 1][row] = vn.y;
      Wns[c4 * 4 + 2][row] = vn.z; Wns[c4 * 4 + 3][row] = vn.w;
    }
#pragma unroll
    for (int it = 0; it < 2; ++it) {
      int i = tid + it * 256;
      int row = i >> 4, c4 = i & 15;
      int gk = k0 + row;
      float4 v = make_float4(0.f, 0.f, 0.f, 0.f);
      if (gk < MSLOTS)
        v = *reinterpret_cast<const float4*>(&mem[(size_t)gk * FDIM + bn0 + c4 * 4]);
      *reinterpret_cast<float4*>(&Ms[row][c4 * 4]) = v;
    }
    __syncthreads();
#pragma unroll
    for (int kk = 0; kk < O2_BK; ++kk) {
      const float* tp = &Wts[kk][tm * 4];
      const float* np = &Wns[kk][tm * 4];
      const float* bp = &Ms[kk][tn * 4];
      float b0 = bp[0], b1 = bp[1], b2 = bp[2], b3 = bp[3];
#pragma unroll
      for (int i = 0; i < 4; ++i) {
        float a = tp[i], cn = np[i];
        at[i][0] = fmaf(a,  b0, at[i][0]); at[i][1] = fmaf(a,  b1, at[i][1]);
        at[i][2] = fmaf(a,  b2, at[i][2]); at[i][3] = fmaf(a,  b3, at[i][3]);
        an[i][0] = fmaf(cn, b0, an[i][0]); an[i][1] = fmaf(cn, b1, an[i][1]);
        an[i][2] = fmaf(cn, b2, an[i][2]); an[i][3] = fmaf(cn, b3, an[i][3]);
      }
    }
    __syncthreads();
  }
  float* outt = out;
  float* outn = out + (size_t)BATCH * FDIM;
#pragma unroll
  for (int i = 0; i < 4; ++i) {
    size_t off = (size_t)(bm0 + tm * 4 + i) * FDIM + bn0 + tn * 4;
    *reinterpret_cast<float4*>(&outt[off]) = make_float4(at[i][0], at[i][1], at[i][2], at[i][3]);
    *reinterpret_cast<float4*>(&outn[off]) = make_float4(an[i][0], an[i][1], an[i][2], an[i][3]);
  }
}

// ======================= host =======================
extern "C" void kernel_launch(void* const* d_in, const int* in_sizes, int n_in,
                              void* d_out, int out_size, void* d_ws, size_t ws_size,
                              hipStream_t stream) {
  const float* z      = (const float*)d_in[0];
  const int*   labels = (const int*)d_in[1];
  const float* mem    = (const float*)d_in[2];
  float* out = (float*)d_out;
  char*  wsb = (char*)d_ws;

  // new-path workspace layout (bytes)
  constexpr size_t NM_B   = 0;
  constexpr size_t NZ_B   = 8192;
  constexpr size_t ZB_B   = 16384;
  constexpr size_t MB_B   = ZB_B + (size_t)BATCH * FDIM * 2;
  constexpr size_t MT_B   = MB_B + (size_t)MPAD * FDIM * 2;
  constexpr size_t WTB_B  = MT_B + (size_t)FDIM * MPAD * 2;
  constexpr size_t WNB_B  = WTB_B + (size_t)BATCH * MPAD * 2;
  constexpr size_t NP_B   = WNB_B + (size_t)BATCH * MPAD * 2;
  constexpr size_t PART_B = NP_B + (size_t)(MPAD + BATCH) * NFB2 * 4;
  constexpr size_t ENT_B  = PART_B + (size_t)SPLITK * BATCH * MPAD * 4;
  constexpr size_t NEED   = ENT_B + 2048;

  if (ws_size >= NEED) {
    float* nm = (float*)(wsb + NM_B);
    float* nz = (float*)(wsb + NZ_B);
    unsigned short* zb = (unsigned short*)(wsb + ZB_B);
    unsigned short* mb = (unsigned short*)(wsb + MB_B);
    unsigned short* mt = (unsigned short*)(wsb + MT_B);
    unsigned short* wt = (unsigned short*)(wsb + WTB_B);
    unsigned short* wn = (unsigned short*)(wsb + WNB_B);
    float* npart = (float*)(wsb + NP_B);
    float* part  = (float*)(wsb + PART_B);
    float* ent   = (float*)(wsb + ENT_B);

    convert_all_kernel<<<dim3(FDIM / 128, (MPAD + BATCH) / 64), 256, 0, stream>>>(
        z, mem, zb, mb, mt, npart);
    normfin_kernel<<<MPAD + BATCH, 64, 0, stream>>>(npart, nm, nz);
    gemm1_mfma<<<dim3(MPAD / G1_BN, BATCH / G1_BM, SPLITK), 256, 0, stream>>>(zb, mb, part);
    softmax2_kernel<<<BATCH, 256, 0, stream>>>(part, nz, nm, labels, wt, wn, ent);
    gemm23_mfma<<<dim3(FDIM / G2_BN, BATCH / G2_BM), 512, 0, stream>>>(wt, wn, mt, out);
    entreduce_kernel<<<1, 256, 0, stream>>>(ent, out);
  } else {
    float* ws    = (float*)d_ws;
    float* nm    = ws + NM_OFF;
    float* nzv   = ws + NZ_OFF;
    float* logit = ws + LOGIT_OFF;
    float* wt    = ws + WT_OFF;
    float* wnt   = ws + WNT_OFF;
    float* ent   = ws + ENT_OFF;

    rownorm_kernel<<<MSLOTS, 256, 0, stream>>>(mem, nm, FDIM);
    rownorm_kernel<<<BATCH, 256, 0, stream>>>(z, nzv, FDIM);
    gemm1_kernel<<<dim3((MSLOTS + O1_BN - 1) / O1_BN, BATCH / O1_BM), 256, 0, stream>>>(
        z, mem, nzv, nm, logit);
    softmax_kernel<<<BATCH, 256, 0, stream>>>(logit, labels, wt, wnt, ent);
    gemm23_kernel<<<dim3(FDIM / O2_BN, BATCH / O2_BM), 256, 0, stream>>>(wt, wnt, mem, out);
    entreduce_kernel<<<1, 256, 0, stream>>>(ent, out);
  }
}